// Round 7
// baseline (199.482 us; speedup 1.0000x reference)
//
#include <hip/hip_runtime.h>

typedef __attribute__((ext_vector_type(8))) short short8;
typedef __attribute__((ext_vector_type(4))) short short4v;
typedef __attribute__((ext_vector_type(4))) float f32x4;
typedef unsigned short u16;

#define QSCALE 0.18033688011112042f   /* 0.125 * log2(e): softmax done in exp2 domain */

#define BB 16
#define LL 1024
#define CC 512
#define HH 8
#define DD 64
#define MROWS (BB*LL)      /* 16384 */
#define KPROJ 1024
#define NPROJ 1536

#define BM 128
#define BN 128
#define BK 32

// workspace offsets (bytes). Vt aliases Xcat (Xcat dead after proj_gemm).
#define WS_XCAT   0ull
#define WS_WCAT   (WS_XCAT + (size_t)MROWS*KPROJ*2)
#define WS_WO     (WS_WCAT + (size_t)NPROJ*KPROJ*2)
#define WS_BIAS   (WS_WO   + (size_t)CC*CC*2)
#define WS_QH     (WS_BIAS + 8192)
#define WS_KH     (WS_QH + (size_t)MROWS*CC*2)
#define WS_VH     (WS_KH + (size_t)MROWS*CC*2)
#define WS_OH     (WS_VH + (size_t)MROWS*CC*2)
#define WS_END    (WS_OH + (size_t)MROWS*CC*2)
#define WS_VT     WS_XCAT

__device__ inline short f2bf(float f) {
  unsigned u = __builtin_bit_cast(unsigned, f);
  u = (u + 0x7FFFu + ((u >> 16) & 1u)) >> 16;
  return (short)u;
}

__device__ inline short8 pack8(const float* src) {
  float4 a = ((const float4*)src)[0];
  float4 b = ((const float4*)src)[1];
  short8 v;
  v[0]=f2bf(a.x); v[1]=f2bf(a.y); v[2]=f2bf(a.z); v[3]=f2bf(a.w);
  v[4]=f2bf(b.x); v[5]=f2bf(b.y); v[6]=f2bf(b.z); v[7]=f2bf(b.w);
  return v;
}

__device__ inline void gload_lds16(const u16* g, char* lds_byte) {
  __builtin_amdgcn_global_load_lds(
      (const __attribute__((address_space(1))) unsigned int*)g,
      (__attribute__((address_space(3))) unsigned int*)lds_byte,
      16, 0, 0);
}

// ---------------- pack kernels ----------------

__global__ __launch_bounds__(256) void pack_x_kernel(
    const float* __restrict__ q, const float* __restrict__ qp, u16* __restrict__ xcat) {
  int o = blockIdx.x * 256 + threadIdx.x;
  int row = o >> 7;
  int kk  = (o & 127) << 3;
  const float* src = (kk < 512) ? (q + (size_t)row * 512 + kk)
                                : (qp + (size_t)row * 512 + (kk - 512));
  short8 v = pack8(src);
  *(short8*)(xcat + (size_t)row * KPROJ + kk) = v;
}

__global__ __launch_bounds__(256) void pack_w_kernel(
    const float* __restrict__ Wqc, const float* __restrict__ Wqp,
    const float* __restrict__ Wkc, const float* __restrict__ Wkp,
    const float* __restrict__ Wv,  const float* __restrict__ Wo,
    const float* __restrict__ bqc, const float* __restrict__ bqp,
    const float* __restrict__ bkc, const float* __restrict__ bkp,
    const float* __restrict__ bv,
    u16* __restrict__ wcat, u16* __restrict__ wo_bf, float* __restrict__ bias_cat) {
  int o = blockIdx.x * 256 + threadIdx.x;
  if (o < 196608) {
    int j = o >> 7;
    int kk = (o & 127) << 3;
    const float* src = nullptr;
    if (j < 512)        src = (kk < 512) ? Wqc + (size_t)j * 512 + kk : Wqp + (size_t)j * 512 + (kk - 512);
    else if (j < 1024) { int jj = j - 512;  src = (kk < 512) ? Wkc + (size_t)jj * 512 + kk : Wkp + (size_t)jj * 512 + (kk - 512); }
    else               { int jj = j - 1024; src = (kk < 512) ? Wv  + (size_t)jj * 512 + kk : nullptr; }
    short8 v = {0,0,0,0,0,0,0,0};
    if (src) v = pack8(src);
    *(short8*)(wcat + (size_t)j * KPROJ + kk) = v;
  } else if (o < 229376) {
    int o2 = o - 196608;
    int j = o2 >> 6;
    int kk = (o2 & 63) << 3;
    short8 v = pack8(Wo + (size_t)j * 512 + kk);
    *(short8*)(wo_bf + (size_t)j * 512 + kk) = v;
  }
  if (o < 1536) {
    float v;
    if (o < 512)       v = bqc[o] + bqp[o];
    else if (o < 1024) v = bkc[o - 512] + bkp[o - 512];
    else               v = bv[o - 1024];
    bias_cat[o] = v;
  }
}

// ---------------- legacy 128x128 GEMM core (out_gemm) ----------------
template <int KDIM>
__device__ inline void gemm_mainloop(const u16* __restrict__ A, const u16* __restrict__ Bw,
                                     int m0, int n0,
                                     u16* Alds, u16* Blds,
                                     f32x4 (&acc)[4][4]) {
  const int tid = threadIdx.x;
  const int lane = tid & 63, wave = tid >> 6;
  const int wr = wave >> 1, wc = wave & 1;
  const int lr = lane & 15, lg = lane >> 4;

  auto stage = [&](int buf, int t) {
    int k0 = t * BK;
    #pragma unroll
    for (int i = 0; i < 2; ++i) {
      int c = (i * 4 + wave) * 64 + lane;
      int row = c >> 2, koct = c & 3;
      char* ldsbaseA = (char*)Alds + (size_t)buf * (BM * BK * 2) + (size_t)(i * 4 + wave) * 1024;
      char* ldsbaseB = (char*)Blds + (size_t)buf * (BN * BK * 2) + (size_t)(i * 4 + wave) * 1024;
      gload_lds16(A  + (size_t)(m0 + row) * KDIM + k0 + koct * 8, ldsbaseA);
      gload_lds16(Bw + (size_t)(n0 + row) * KDIM + k0 + koct * 8, ldsbaseB);
    }
  };

  stage(0, 0);
  constexpr int NT = KDIM / BK;
  int cur = 0;
  for (int t = 0; t < NT; ++t) {
    __syncthreads();
    if (t + 1 < NT) stage(cur ^ 1, t + 1);
    const u16* Ab = Alds + (size_t)cur * (BM * BK);
    const u16* Bb = Blds + (size_t)cur * (BN * BK);
    short8 af[4], bfr[4];
    #pragma unroll
    for (int m = 0; m < 4; ++m)
      af[m] = *(const short8*)(Ab + (size_t)(wr * 64 + m * 16 + lr) * BK + lg * 8);
    #pragma unroll
    for (int n = 0; n < 4; ++n)
      bfr[n] = *(const short8*)(Bb + (size_t)(wc * 64 + n * 16 + lr) * BK + lg * 8);
    #pragma unroll
    for (int m = 0; m < 4; ++m)
      #pragma unroll
      for (int n = 0; n < 4; ++n)
        acc[m][n] = __builtin_amdgcn_mfma_f32_16x16x32_bf16(af[m], bfr[n], acc[m][n], 0, 0, 0);
    cur ^= 1;
  }
}

// ---------------- projection GEMM: 256x256 tile, BK=64, 8 waves ----------------
__global__ __launch_bounds__(512, 2) void proj_gemm_kernel(
    const u16* __restrict__ Xcat, const u16* __restrict__ Wcat,
    const float* __restrict__ bias_cat,
    u16* __restrict__ Qh, u16* __restrict__ Kh, u16* __restrict__ Vh) {
  __shared__ __align__(16) u16 lds[2 * 32768];   // 128 KB

  // bijective XCD swizzle (384 blocks, 384 % 8 == 0)
  int id0 = blockIdx.x;
  int swz = (id0 & 7) * 48 + (id0 >> 3);
  int bx = swz / 6, by = swz % 6;
  const int m0 = bx * 256, n0 = by * 256;

  const int tid = threadIdx.x;
  const int lane = tid & 63, wave = tid >> 6;
  const int wr = wave >> 2, wc = wave & 3;
  const int lr = lane & 15, lg = lane >> 4;

  auto stage_half = [&](int buf, int u, int i, int k0) {
    const u16* base = (u < 2) ? (Xcat + (size_t)(m0 + u * 128) * KPROJ + k0)
                              : (Wcat + (size_t)(n0 + (u - 2) * 128) * KPROJ + k0);
    int s = i * 512 + tid;
    int row = s >> 3, col = s & 7;
    int colp = col ^ (row & 7);              // inverse swizzle on SOURCE, linear dest
    gload_lds16(base + (size_t)row * KPROJ + colp * 8,
                (char*)lds + ((size_t)buf * 32768 + (size_t)u * 8192) * 2
                           + (size_t)(i * 512 + wave * 64) * 16);
  };

  auto rdW = [&](int buf, int nf, int ks) {
    int rowl = (wc & 1) * 64 + nf * 16 + lr;
    int chunk = (ks * 4 + lg) ^ (rowl & 7);
    return *(const short8*)(lds + (size_t)buf * 32768 + (size_t)(2 + (wc >> 1)) * 8192
                            + (size_t)rowl * 64 + chunk * 8);
  };
  auto rdX = [&](int buf, int mf, int ks) {
    int rowl = mf * 16 + lr;
    int chunk = (ks * 4 + lg) ^ (rowl & 7);
    return *(const short8*)(lds + (size_t)buf * 32768 + (size_t)wr * 8192
                            + (size_t)rowl * 64 + chunk * 8);
  };

  f32x4 acc[8][4];
  f32x4 z4 = {0.f, 0.f, 0.f, 0.f};
  #pragma unroll
  for (int mf = 0; mf < 8; ++mf)
    #pragma unroll
    for (int nf = 0; nf < 4; ++nf) acc[mf][nf] = z4;

  #pragma unroll
  for (int u = 0; u < 4; ++u) {
    stage_half(0, u, 0, 0);
    stage_half(0, u, 1, 0);
  }
  asm volatile("s_waitcnt vmcnt(0)" ::: "memory");
  __builtin_amdgcn_s_barrier();
  __builtin_amdgcn_sched_barrier(0);

  short8 wfr[4][2];
  constexpr int NT = KPROJ / 64;   // 16 K-tiles
  for (int kt = 0; kt < NT; ++kt) {
    const int b = kt & 1;
    const bool pf = (kt + 1 < NT);
    const int k1 = (kt + 1) * 64;
    #pragma unroll
    for (int p = 0; p < 4; ++p) {
      if (p == 0) {
        #pragma unroll
        for (int nf = 0; nf < 4; ++nf)
          #pragma unroll
          for (int ks = 0; ks < 2; ++ks) wfr[nf][ks] = rdW(b, nf, ks);
      }
      short8 xf[2][2];
      #pragma unroll
      for (int mm = 0; mm < 2; ++mm)
        #pragma unroll
        for (int ks = 0; ks < 2; ++ks) xf[mm][ks] = rdX(b, p * 2 + mm, ks);
      // consumption-ordered prefetch of tile kt+1 into the dead buffer
      if (pf) {
        if (p == 0)      { stage_half(b ^ 1, 2, 0, k1); stage_half(b ^ 1, 2, 1, k1); }
        else if (p == 1) { stage_half(b ^ 1, 3, 0, k1); stage_half(b ^ 1, 3, 1, k1); }
        else if (p == 2) { stage_half(b ^ 1, 0, 0, k1); stage_half(b ^ 1, 1, 0, k1); }
        else             { stage_half(b ^ 1, 0, 1, k1); stage_half(b ^ 1, 1, 1, k1); }
      }
      __builtin_amdgcn_s_barrier();
      __builtin_amdgcn_sched_barrier(0);
      __builtin_amdgcn_s_setprio(1);
      #pragma unroll
      for (int mm = 0; mm < 2; ++mm)
        #pragma unroll
        for (int nf = 0; nf < 4; ++nf)
          #pragma unroll
          for (int ks = 0; ks < 2; ++ks)
            acc[p * 2 + mm][nf] = __builtin_amdgcn_mfma_f32_16x16x32_bf16(
                wfr[nf][ks], xf[mm][ks], acc[p * 2 + mm][nf], 0, 0, 0);
      __builtin_amdgcn_s_setprio(0);
      if (p == 1) asm volatile("s_waitcnt vmcnt(4)" ::: "memory");
      if (p == 3) asm volatile("s_waitcnt vmcnt(2)" ::: "memory");
      __builtin_amdgcn_s_barrier();
      __builtin_amdgcn_sched_barrier(0);
    }
  }

  const int cbase = n0 + wc * 64 + lg * 4;
  #pragma unroll
  for (int mf = 0; mf < 8; ++mf) {
    int lglob = m0 + wr * 128 + mf * 16 + lr;
    int bidx = lglob >> 10, lrow = lglob & 1023;
    #pragma unroll
    for (int nf = 0; nf < 4; ++nf) {
      int c = cbase + nf * 16;
      float4 bb = *(const float4*)&bias_cat[c];
      int sec = c >> 9, cj = c & 511;
      int h = cj >> 6, d0 = cj & 63;
      size_t idx = ((size_t)(bidx * HH + h) * LL + lrow) * DD + d0;
      float v0 = acc[mf][nf][0] + bb.x;
      float v1 = acc[mf][nf][1] + bb.y;
      float v2 = acc[mf][nf][2] + bb.z;
      float v3 = acc[mf][nf][3] + bb.w;
      if (sec == 0) { v0 *= QSCALE; v1 *= QSCALE; v2 *= QSCALE; v3 *= QSCALE; }
      short4v o;
      o[0] = f2bf(v0); o[1] = f2bf(v1); o[2] = f2bf(v2); o[3] = f2bf(v3);
      u16* dst = (sec == 0) ? Qh : (sec == 1) ? Kh : Vh;
      *(short4v*)&dst[idx] = o;
    }
  }
}

// ---------------- V transpose: Vh[bh][l][d] -> Vt[bh][d][l] ----------------
__global__ __launch_bounds__(256) void vtrans_kernel(
    const u16* __restrict__ Vh, u16* __restrict__ Vt) {
  __shared__ u16 T[64][72];
  int bh = blockIdx.y;
  int l0 = blockIdx.x * 64;
  int t = threadIdx.x;
  const u16* src = Vh + (size_t)bh * LL * DD;
  {
    int l = t >> 2, dq = (t & 3) * 16;
    short8 v0 = *(const short8*)(src + (size_t)(l0 + l) * DD + dq);
    short8 v1 = *(const short8*)(src + (size_t)(l0 + l) * DD + dq + 8);
    #pragma unroll
    for (int j = 0; j < 8; ++j) T[dq + j][l] = (u16)v0[j];
    #pragma unroll
    for (int j = 0; j < 8; ++j) T[dq + 8 + j][l] = (u16)v1[j];
  }
  __syncthreads();
  {
    int d = t >> 2, lq = (t & 3) * 16;
    u16* dst = Vt + (size_t)bh * DD * LL + (size_t)d * LL + l0 + lq;
    *(short8*)dst = *(const short8*)&T[d][lq];
    *(short8*)(dst + 8) = *(const short8*)&T[d][lq + 8];
  }
}

// ---------------- flash attention (transposed-softmax, 4 blocks/CU) ----------------
// LDS 32KB: K/V double-buffered; the P-transpose buffer ALIASES Kl[cur] (K-tile
// is dead after QK^T; a barrier between softmax and the first P write makes all
// waves' QK reads complete; P regions are wave-private; next-tile staging into
// Kl[cur] is issued only after the end-of-tile barrier). V fragments hoisted to
// registers once per tile (shared by both m halves).
__global__ __launch_bounds__(256, 4) void attn_kernel(
    const u16* __restrict__ Qh, const u16* __restrict__ Kh,
    const u16* __restrict__ Vt, u16* __restrict__ Oh) {
  __shared__ __align__(16) u16 Kl[2][64 * 64];
  __shared__ __align__(16) u16 Vl[2][64 * 64];

  const int tid = threadIdx.x;
  const int lane = tid & 63, wave = tid >> 6;
  const int lr = lane & 15, lg = lane >> 4;
  const int sw = (lr & 7) * 2;
  int n = blockIdx.x;
  int kk = n >> 3;
  const int bh = (n & 7) * 16 + (kk >> 3);
  const int q0 = (kk & 7) * 128;

  const u16* Qb = Qh + (size_t)bh * LL * DD;
  const u16* Kb = Kh + (size_t)bh * LL * DD;
  const u16* Vb = Vt + (size_t)bh * DD * LL;

  short8 aq[2][2];
  #pragma unroll
  for (int m = 0; m < 2; ++m)
    #pragma unroll
    for (int s = 0; s < 2; ++s)
      aq[m][s] = *(const short8*)(Qb + (size_t)(q0 + wave * 32 + m * 16 + lr) * DD + s * 32 + lg * 8);

  f32x4 z4 = {0.f, 0.f, 0.f, 0.f};
  f32x4 oaccT[2][4];
  #pragma unroll
  for (int m = 0; m < 2; ++m)
    #pragma unroll
    for (int db = 0; db < 4; ++db) oaccT[m][db] = z4;
  float mrow[2] = {-3e38f, -3e38f}, lsum[2] = {0.f, 0.f};

  auto stage = [&](int buf, int kt) {
    int kk0 = kt * 64;
    #pragma unroll
    for (int i = 0; i < 2; ++i) {
      int c = i * 256 + wave * 64 + lane;
      int row = c >> 3, koct = c & 7;
      int ks = koct ^ (row & 7);
      gload_lds16(Kb + (size_t)(kk0 + row) * DD + ks * 8,
                  (char*)&Kl[buf][0] + (size_t)(i * 4 + wave) * 1024);
      gload_lds16(Vb + (size_t)row * LL + kk0 + ks * 8,
                  (char*)&Vl[buf][0] + (size_t)(i * 4 + wave) * 1024);
    }
  };

  stage(0, 0);
  int cur = 0;
  for (int kt = 0; kt < 16; ++kt) {
    if (kt + 1 < 16) {
      stage(cur ^ 1, kt + 1);
      asm volatile("s_waitcnt vmcnt(4)" ::: "memory");
    } else {
      asm volatile("s_waitcnt vmcnt(0)" ::: "memory");
    }
    __builtin_amdgcn_s_barrier();
    __builtin_amdgcn_sched_barrier(0);

    // ---- S^T = K @ Q^T ----
    f32x4 ps[2][4];
    #pragma unroll
    for (int m = 0; m < 2; ++m)
      #pragma unroll
      for (int kb = 0; kb < 4; ++kb) ps[m][kb] = z4;
    __builtin_amdgcn_s_setprio(1);
    #pragma unroll
    for (int s = 0; s < 2; ++s) {
      #pragma unroll
      for (int kb = 0; kb < 4; ++kb) {
        int key = kb * 16 + lr;
        int dct = s * 4 + lg;
        short8 ka = *(const short8*)((const char*)&Kl[cur][0] + (size_t)key * 128 + ((dct ^ (key & 7)) << 4));
        ps[0][kb] = __builtin_amdgcn_mfma_f32_16x16x32_bf16(ka, aq[0][s], ps[0][kb], 0, 0, 0);
        ps[1][kb] = __builtin_amdgcn_mfma_f32_16x16x32_bf16(ka, aq[1][s], ps[1][kb], 0, 0, 0);
      }
    }
    __builtin_amdgcn_s_setprio(0);

    // ---- lane-local online softmax with defer-max; pack P to bf16 early ----
    uint2 pk[2][4];
    #pragma unroll
    for (int m = 0; m < 2; ++m) {
      // max3-friendly reduction (left-nested triples)
      float a0 = fmaxf(fmaxf(fmaxf(ps[m][0][0], ps[m][0][1]), ps[m][0][2]), ps[m][0][3]);
      float a1 = fmaxf(fmaxf(fmaxf(ps[m][1][0], ps[m][1][1]), ps[m][1][2]), ps[m][1][3]);
      float a2 = fmaxf(fmaxf(fmaxf(ps[m][2][0], ps[m][2][1]), ps[m][2][2]), ps[m][2][3]);
      float a3 = fmaxf(fmaxf(fmaxf(ps[m][3][0], ps[m][3][1]), ps[m][3][2]), ps[m][3][3]);
      float pmax = fmaxf(fmaxf(fmaxf(a0, a1), a2), a3);
      pmax = fmaxf(pmax, __shfl_xor(pmax, 16));
      pmax = fmaxf(pmax, __shfl_xor(pmax, 32));
      if (!__all(pmax <= mrow[m] + 8.f)) {
        float mn = fmaxf(mrow[m], pmax);
        float alpha = exp2f(mrow[m] - mn);
        mrow[m] = mn;
        lsum[m] *= alpha;
        #pragma unroll
        for (int db = 0; db < 4; ++db)
          #pragma unroll
          for (int r = 0; r < 4; ++r) oaccT[m][db][r] *= alpha;
      }
      float rs = 0.f;
      #pragma unroll
      for (int kb = 0; kb < 4; ++kb) {
        #pragma unroll
        for (int r = 0; r < 4; ++r) {
          float p = exp2f(ps[m][kb][r] - mrow[m]);
          ps[m][kb][r] = p;
          rs += p;
        }
        unsigned lo, hi;
        asm("v_cvt_pk_bf16_f32 %0, %1, %2" : "=v"(lo) : "v"(ps[m][kb][0]), "v"(ps[m][kb][1]));
        asm("v_cvt_pk_bf16_f32 %0, %1, %2" : "=v"(hi) : "v"(ps[m][kb][2]), "v"(ps[m][kb][3]));
        pk[m][kb].x = lo; pk[m][kb].y = hi;
      }
      rs += __shfl_xor(rs, 16);
      rs += __shfl_xor(rs, 32);
      lsum[m] += rs;
    }

    // ---- hoist V fragments (Vl[cur], shared by both m) ----
    short8 bv[2][4];
    #pragma unroll
    for (int s = 0; s < 2; ++s)
      #pragma unroll
      for (int db = 0; db < 4; ++db) {
        int d = db * 16 + lr;
        int kct = s * 4 + lg;
        bv[s][db] = *(const short8*)((const char*)&Vl[cur][0] + (size_t)d * 128 + ((kct ^ (d & 7)) << 4));
      }

    // Kl[cur] is dead to QK after this barrier -> reuse as per-wave P buffer
    __builtin_amdgcn_s_barrier();
    char* Pw = (char*)&Kl[cur][0] + (size_t)wave * 2048;

    // ---- O^T += V^T @ P, sequential m through the aliased P buffer ----
    __builtin_amdgcn_s_setprio(1);
    #pragma unroll
    for (int m = 0; m < 2; ++m) {
      #pragma unroll
      for (int kb = 0; kb < 4; ++kb)
        *(uint2*)(Pw + lr * 128 + ((((kb * 4 + lg) ^ sw)) << 3)) = pk[m][kb];
      asm volatile("s_waitcnt lgkmcnt(0)" ::: "memory");
      __builtin_amdgcn_sched_barrier(0);
      #pragma unroll
      for (int s = 0; s < 2; ++s) {
        int val0 = s * 8 + lg * 2;
        uint4 pw = *(const uint4*)(Pw + lr * 128 + (((val0 ^ sw)) << 3));
        short8 ap = __builtin_bit_cast(short8, pw);
        #pragma unroll
        for (int db = 0; db < 4; ++db)
          oaccT[m][db] = __builtin_amdgcn_mfma_f32_16x16x32_bf16(bv[s][db], ap, oaccT[m][db], 0, 0, 0);
      }
    }
    __builtin_amdgcn_s_setprio(0);

    __builtin_amdgcn_s_barrier();
    cur ^= 1;
  }

  int b = bh >> 3, h = bh & 7;
  #pragma unroll
  for (int m = 0; m < 2; ++m) {
    float inv = 1.0f / lsum[m];
    int q = q0 + wave * 32 + m * 16 + lr;
    #pragma unroll
    for (int db = 0; db < 4; ++db) {
      int d0 = db * 16 + lg * 4;
      short4v o;
      #pragma unroll
      for (int r = 0; r < 4; ++r) o[r] = f2bf(oaccT[m][db][r] * inv);
      *(short4v*)&Oh[(size_t)(b * LL + q) * CC + h * 64 + d0] = o;
    }
  }
}

// ---------------- output projection + residual ----------------
__global__ __launch_bounds__(256) void out_gemm_kernel(
    const u16* __restrict__ Oh, const u16* __restrict__ Wo_bf,
    const float* __restrict__ bo, const float* __restrict__ query,
    float* __restrict__ out) {
  __shared__ __align__(16) u16 Alds[2 * BM * BK];
  __shared__ __align__(16) u16 Blds[2 * BN * BK];
  int m0 = blockIdx.x * BM, n0 = blockIdx.y * BN;
  f32x4 acc[4][4];
  f32x4 z4 = {0.f, 0.f, 0.f, 0.f};
  #pragma unroll
  for (int m = 0; m < 4; ++m)
    #pragma unroll
    for (int n = 0; n < 4; ++n) acc[m][n] = z4;

  gemm_mainloop<CC>(Oh, Wo_bf, m0, n0, Alds, Blds, acc);

  const int lane = threadIdx.x & 63, wave = threadIdx.x >> 6;
  const int wr = wave >> 1, wc = wave & 1;
  const int lr = lane & 15, lg = lane >> 4;
  #pragma unroll
  for (int m = 0; m < 4; ++m) {
    int rowb = m0 + wr * 64 + m * 16 + lg * 4;
    #pragma unroll
    for (int n = 0; n < 4; ++n) {
      int col = n0 + wc * 64 + n * 16 + lr;
      float bias = bo[col];
      #pragma unroll
      for (int r = 0; r < 4; ++r) {
        int rw = rowb + r;
        size_t idx = (size_t)rw * CC + col;
        out[idx] = acc[m][n][r] + bias + query[idx];
      }
    }
  }
}

// ---------------- launcher ----------------
extern "C" void kernel_launch(void* const* d_in, const int* in_sizes, int n_in,
                              void* d_out, int out_size, void* d_ws, size_t ws_size,
                              hipStream_t stream) {
  (void)in_sizes; (void)n_in; (void)out_size;
  const float* query = (const float*)d_in[0];
  const float* qpos  = (const float*)d_in[1];
  const float* Wqc = (const float*)d_in[2];
  const float* bqc = (const float*)d_in[3];
  const float* Wqp = (const float*)d_in[4];
  const float* bqp = (const float*)d_in[5];
  const float* Wkc = (const float*)d_in[6];
  const float* bkc = (const float*)d_in[7];
  const float* Wkp = (const float*)d_in[8];
  const float* bkp = (const float*)d_in[9];
  const float* Wv  = (const float*)d_in[10];
  const float* bv  = (const float*)d_in[11];
  const float* Wo  = (const float*)d_in[12];
  const float* bo  = (const float*)d_in[13];

  char* ws = (char*)d_ws;
  if (ws_size < WS_END) return;

  u16*   Xcat     = (u16*)(ws + WS_XCAT);
  u16*   Wcat     = (u16*)(ws + WS_WCAT);
  u16*   Wo_bf    = (u16*)(ws + WS_WO);
  float* bias_cat = (float*)(ws + WS_BIAS);
  u16*   Qh       = (u16*)(ws + WS_QH);
  u16*   Kh       = (u16*)(ws + WS_KH);
  u16*   Vh       = (u16*)(ws + WS_VH);
  u16*   Oh       = (u16*)(ws + WS_OH);
  u16*   Vtr      = (u16*)(ws + WS_VT);   // aliases Xcat (dead after proj)
  float* out      = (float*)d_out;

  pack_x_kernel<<<dim3(8192), dim3(256), 0, stream>>>(query, qpos, Xcat);
  pack_w_kernel<<<dim3(896), dim3(256), 0, stream>>>(Wqc, Wqp, Wkc, Wkp, Wv, Wo,
                                                     bqc, bqp, bkc, bkp, bv,
                                                     Wcat, Wo_bf, bias_cat);
  proj_gemm_kernel<<<dim3((MROWS / 256) * (NPROJ / 256)), dim3(512), 0, stream>>>(
      Xcat, Wcat, bias_cat, Qh, Kh, Vh);
  vtrans_kernel<<<dim3(LL / 64, BB * HH), dim3(256), 0, stream>>>(Vh, Vtr);
  attn_kernel<<<dim3(1024), dim3(256), 0, stream>>>(Qh, Kh, Vtr, Oh);
  out_gemm_kernel<<<dim3(MROWS / BM, CC / BN), dim3(256), 0, stream>>>(
      Oh, Wo_bf, bo, query, out);
}

// Round 8
// 169.631 us; speedup vs baseline: 1.1760x; 1.1760x over previous
//
#include <hip/hip_runtime.h>

typedef __attribute__((ext_vector_type(8))) short short8;
typedef __attribute__((ext_vector_type(4))) short short4v;
typedef __attribute__((ext_vector_type(4))) float f32x4;
typedef unsigned short u16;

#define QSCALE 0.18033688011112042f   /* 0.125 * log2(e): softmax done in exp2 domain */

#define BB 16
#define LL 1024
#define CC 512
#define HH 8
#define DD 64
#define MROWS (BB*LL)      /* 16384 */
#define KPROJ 1024
#define NPROJ 1536

#define BM 128
#define BN 128
#define BK 32

// workspace offsets (bytes). Vt aliases Xcat (Xcat dead after proj_gemm).
#define WS_XCAT   0ull
#define WS_WCAT   (WS_XCAT + (size_t)MROWS*KPROJ*2)
#define WS_WO     (WS_WCAT + (size_t)NPROJ*KPROJ*2)
#define WS_BIAS   (WS_WO   + (size_t)CC*CC*2)
#define WS_QH     (WS_BIAS + 8192)
#define WS_KH     (WS_QH + (size_t)MROWS*CC*2)
#define WS_VH     (WS_KH + (size_t)MROWS*CC*2)
#define WS_OH     (WS_VH + (size_t)MROWS*CC*2)
#define WS_END    (WS_OH + (size_t)MROWS*CC*2)
#define WS_VT     WS_XCAT

__device__ inline short f2bf(float f) {
  unsigned u = __builtin_bit_cast(unsigned, f);
  u = (u + 0x7FFFu + ((u >> 16) & 1u)) >> 16;
  return (short)u;
}

__device__ inline short8 pack8(const float* src) {
  float4 a = ((const float4*)src)[0];
  float4 b = ((const float4*)src)[1];
  short8 v;
  v[0]=f2bf(a.x); v[1]=f2bf(a.y); v[2]=f2bf(a.z); v[3]=f2bf(a.w);
  v[4]=f2bf(b.x); v[5]=f2bf(b.y); v[6]=f2bf(b.z); v[7]=f2bf(b.w);
  return v;
}

__device__ inline void gload_lds16(const u16* g, char* lds_byte) {
  __builtin_amdgcn_global_load_lds(
      (const __attribute__((address_space(1))) unsigned int*)g,
      (__attribute__((address_space(3))) unsigned int*)lds_byte,
      16, 0, 0);
}

// ---------------- pack kernels ----------------

__global__ __launch_bounds__(256) void pack_x_kernel(
    const float* __restrict__ q, const float* __restrict__ qp, u16* __restrict__ xcat) {
  int o = blockIdx.x * 256 + threadIdx.x;
  int row = o >> 7;
  int kk  = (o & 127) << 3;
  const float* src = (kk < 512) ? (q + (size_t)row * 512 + kk)
                                : (qp + (size_t)row * 512 + (kk - 512));
  short8 v = pack8(src);
  *(short8*)(xcat + (size_t)row * KPROJ + kk) = v;
}

__global__ __launch_bounds__(256) void pack_w_kernel(
    const float* __restrict__ Wqc, const float* __restrict__ Wqp,
    const float* __restrict__ Wkc, const float* __restrict__ Wkp,
    const float* __restrict__ Wv,  const float* __restrict__ Wo,
    const float* __restrict__ bqc, const float* __restrict__ bqp,
    const float* __restrict__ bkc, const float* __restrict__ bkp,
    const float* __restrict__ bv,
    u16* __restrict__ wcat, u16* __restrict__ wo_bf, float* __restrict__ bias_cat) {
  int o = blockIdx.x * 256 + threadIdx.x;
  if (o < 196608) {
    int j = o >> 7;
    int kk = (o & 127) << 3;
    const float* src = nullptr;
    if (j < 512)        src = (kk < 512) ? Wqc + (size_t)j * 512 + kk : Wqp + (size_t)j * 512 + (kk - 512);
    else if (j < 1024) { int jj = j - 512;  src = (kk < 512) ? Wkc + (size_t)jj * 512 + kk : Wkp + (size_t)jj * 512 + (kk - 512); }
    else               { int jj = j - 1024; src = (kk < 512) ? Wv  + (size_t)jj * 512 + kk : nullptr; }
    short8 v = {0,0,0,0,0,0,0,0};
    if (src) v = pack8(src);
    *(short8*)(wcat + (size_t)j * KPROJ + kk) = v;
  } else if (o < 229376) {
    int o2 = o - 196608;
    int j = o2 >> 6;
    int kk = (o2 & 63) << 3;
    short8 v = pack8(Wo + (size_t)j * 512 + kk);
    *(short8*)(wo_bf + (size_t)j * 512 + kk) = v;
  }
  if (o < 1536) {
    float v;
    if (o < 512)       v = bqc[o] + bqp[o];
    else if (o < 1024) v = bkc[o - 512] + bkp[o - 512];
    else               v = bv[o - 1024];
    bias_cat[o] = v;
  }
}

// ---------------- legacy 128x128 GEMM core (out_gemm) ----------------
template <int KDIM>
__device__ inline void gemm_mainloop(const u16* __restrict__ A, const u16* __restrict__ Bw,
                                     int m0, int n0,
                                     u16* Alds, u16* Blds,
                                     f32x4 (&acc)[4][4]) {
  const int tid = threadIdx.x;
  const int lane = tid & 63, wave = tid >> 6;
  const int wr = wave >> 1, wc = wave & 1;
  const int lr = lane & 15, lg = lane >> 4;

  auto stage = [&](int buf, int t) {
    int k0 = t * BK;
    #pragma unroll
    for (int i = 0; i < 2; ++i) {
      int c = (i * 4 + wave) * 64 + lane;
      int row = c >> 2, koct = c & 3;
      char* ldsbaseA = (char*)Alds + (size_t)buf * (BM * BK * 2) + (size_t)(i * 4 + wave) * 1024;
      char* ldsbaseB = (char*)Blds + (size_t)buf * (BN * BK * 2) + (size_t)(i * 4 + wave) * 1024;
      gload_lds16(A  + (size_t)(m0 + row) * KDIM + k0 + koct * 8, ldsbaseA);
      gload_lds16(Bw + (size_t)(n0 + row) * KDIM + k0 + koct * 8, ldsbaseB);
    }
  };

  stage(0, 0);
  constexpr int NT = KDIM / BK;
  int cur = 0;
  for (int t = 0; t < NT; ++t) {
    __syncthreads();
    if (t + 1 < NT) stage(cur ^ 1, t + 1);
    const u16* Ab = Alds + (size_t)cur * (BM * BK);
    const u16* Bb = Blds + (size_t)cur * (BN * BK);
    short8 af[4], bfr[4];
    #pragma unroll
    for (int m = 0; m < 4; ++m)
      af[m] = *(const short8*)(Ab + (size_t)(wr * 64 + m * 16 + lr) * BK + lg * 8);
    #pragma unroll
    for (int n = 0; n < 4; ++n)
      bfr[n] = *(const short8*)(Bb + (size_t)(wc * 64 + n * 16 + lr) * BK + lg * 8);
    #pragma unroll
    for (int m = 0; m < 4; ++m)
      #pragma unroll
      for (int n = 0; n < 4; ++n)
        acc[m][n] = __builtin_amdgcn_mfma_f32_16x16x32_bf16(af[m], bfr[n], acc[m][n], 0, 0, 0);
    cur ^= 1;
  }
}

// ---------------- projection GEMM: 256x256 tile, BK=64, 8 waves ----------------
__global__ __launch_bounds__(512, 2) void proj_gemm_kernel(
    const u16* __restrict__ Xcat, const u16* __restrict__ Wcat,
    const float* __restrict__ bias_cat,
    u16* __restrict__ Qh, u16* __restrict__ Kh, u16* __restrict__ Vh) {
  __shared__ __align__(16) u16 lds[2 * 32768];   // 128 KB

  // bijective XCD swizzle (384 blocks, 384 % 8 == 0)
  int id0 = blockIdx.x;
  int swz = (id0 & 7) * 48 + (id0 >> 3);
  int bx = swz / 6, by = swz % 6;
  const int m0 = bx * 256, n0 = by * 256;

  const int tid = threadIdx.x;
  const int lane = tid & 63, wave = tid >> 6;
  const int wr = wave >> 2, wc = wave & 3;
  const int lr = lane & 15, lg = lane >> 4;

  auto stage_half = [&](int buf, int u, int i, int k0) {
    const u16* base = (u < 2) ? (Xcat + (size_t)(m0 + u * 128) * KPROJ + k0)
                              : (Wcat + (size_t)(n0 + (u - 2) * 128) * KPROJ + k0);
    int s = i * 512 + tid;
    int row = s >> 3, col = s & 7;
    int colp = col ^ (row & 7);              // inverse swizzle on SOURCE, linear dest
    gload_lds16(base + (size_t)row * KPROJ + colp * 8,
                (char*)lds + ((size_t)buf * 32768 + (size_t)u * 8192) * 2
                           + (size_t)(i * 512 + wave * 64) * 16);
  };

  auto rdW = [&](int buf, int nf, int ks) {
    int rowl = (wc & 1) * 64 + nf * 16 + lr;
    int chunk = (ks * 4 + lg) ^ (rowl & 7);
    return *(const short8*)(lds + (size_t)buf * 32768 + (size_t)(2 + (wc >> 1)) * 8192
                            + (size_t)rowl * 64 + chunk * 8);
  };
  auto rdX = [&](int buf, int mf, int ks) {
    int rowl = mf * 16 + lr;
    int chunk = (ks * 4 + lg) ^ (rowl & 7);
    return *(const short8*)(lds + (size_t)buf * 32768 + (size_t)wr * 8192
                            + (size_t)rowl * 64 + chunk * 8);
  };

  f32x4 acc[8][4];
  f32x4 z4 = {0.f, 0.f, 0.f, 0.f};
  #pragma unroll
  for (int mf = 0; mf < 8; ++mf)
    #pragma unroll
    for (int nf = 0; nf < 4; ++nf) acc[mf][nf] = z4;

  #pragma unroll
  for (int u = 0; u < 4; ++u) {
    stage_half(0, u, 0, 0);
    stage_half(0, u, 1, 0);
  }
  asm volatile("s_waitcnt vmcnt(0)" ::: "memory");
  __builtin_amdgcn_s_barrier();
  __builtin_amdgcn_sched_barrier(0);

  short8 wfr[4][2];
  constexpr int NT = KPROJ / 64;   // 16 K-tiles
  for (int kt = 0; kt < NT; ++kt) {
    const int b = kt & 1;
    const bool pf = (kt + 1 < NT);
    const int k1 = (kt + 1) * 64;
    #pragma unroll
    for (int p = 0; p < 4; ++p) {
      if (p == 0) {
        #pragma unroll
        for (int nf = 0; nf < 4; ++nf)
          #pragma unroll
          for (int ks = 0; ks < 2; ++ks) wfr[nf][ks] = rdW(b, nf, ks);
      }
      short8 xf[2][2];
      #pragma unroll
      for (int mm = 0; mm < 2; ++mm)
        #pragma unroll
        for (int ks = 0; ks < 2; ++ks) xf[mm][ks] = rdX(b, p * 2 + mm, ks);
      // consumption-ordered prefetch of tile kt+1 into the dead buffer
      if (pf) {
        if (p == 0)      { stage_half(b ^ 1, 2, 0, k1); stage_half(b ^ 1, 2, 1, k1); }
        else if (p == 1) { stage_half(b ^ 1, 3, 0, k1); stage_half(b ^ 1, 3, 1, k1); }
        else if (p == 2) { stage_half(b ^ 1, 0, 0, k1); stage_half(b ^ 1, 1, 0, k1); }
        else             { stage_half(b ^ 1, 0, 1, k1); stage_half(b ^ 1, 1, 1, k1); }
      }
      __builtin_amdgcn_s_barrier();
      __builtin_amdgcn_sched_barrier(0);
      __builtin_amdgcn_s_setprio(1);
      #pragma unroll
      for (int mm = 0; mm < 2; ++mm)
        #pragma unroll
        for (int nf = 0; nf < 4; ++nf)
          #pragma unroll
          for (int ks = 0; ks < 2; ++ks)
            acc[p * 2 + mm][nf] = __builtin_amdgcn_mfma_f32_16x16x32_bf16(
                wfr[nf][ks], xf[mm][ks], acc[p * 2 + mm][nf], 0, 0, 0);
      __builtin_amdgcn_s_setprio(0);
      if (p == 1) asm volatile("s_waitcnt vmcnt(4)" ::: "memory");
      if (p == 3) asm volatile("s_waitcnt vmcnt(2)" ::: "memory");
      __builtin_amdgcn_s_barrier();
      __builtin_amdgcn_sched_barrier(0);
    }
  }

  const int cbase = n0 + wc * 64 + lg * 4;
  #pragma unroll
  for (int mf = 0; mf < 8; ++mf) {
    int lglob = m0 + wr * 128 + mf * 16 + lr;
    int bidx = lglob >> 10, lrow = lglob & 1023;
    #pragma unroll
    for (int nf = 0; nf < 4; ++nf) {
      int c = cbase + nf * 16;
      float4 bb = *(const float4*)&bias_cat[c];
      int sec = c >> 9, cj = c & 511;
      int h = cj >> 6, d0 = cj & 63;
      size_t idx = ((size_t)(bidx * HH + h) * LL + lrow) * DD + d0;
      float v0 = acc[mf][nf][0] + bb.x;
      float v1 = acc[mf][nf][1] + bb.y;
      float v2 = acc[mf][nf][2] + bb.z;
      float v3 = acc[mf][nf][3] + bb.w;
      if (sec == 0) { v0 *= QSCALE; v1 *= QSCALE; v2 *= QSCALE; v3 *= QSCALE; }
      short4v o;
      o[0] = f2bf(v0); o[1] = f2bf(v1); o[2] = f2bf(v2); o[3] = f2bf(v3);
      u16* dst = (sec == 0) ? Qh : (sec == 1) ? Kh : Vh;
      *(short4v*)&dst[idx] = o;
    }
  }
}

// ---------------- V transpose: Vh[bh][l][d] -> Vt[bh][d][l] ----------------
__global__ __launch_bounds__(256) void vtrans_kernel(
    const u16* __restrict__ Vh, u16* __restrict__ Vt) {
  __shared__ u16 T[64][72];
  int bh = blockIdx.y;
  int l0 = blockIdx.x * 64;
  int t = threadIdx.x;
  const u16* src = Vh + (size_t)bh * LL * DD;
  {
    int l = t >> 2, dq = (t & 3) * 16;
    short8 v0 = *(const short8*)(src + (size_t)(l0 + l) * DD + dq);
    short8 v1 = *(const short8*)(src + (size_t)(l0 + l) * DD + dq + 8);
    #pragma unroll
    for (int j = 0; j < 8; ++j) T[dq + j][l] = (u16)v0[j];
    #pragma unroll
    for (int j = 0; j < 8; ++j) T[dq + 8 + j][l] = (u16)v1[j];
  }
  __syncthreads();
  {
    int d = t >> 2, lq = (t & 3) * 16;
    u16* dst = Vt + (size_t)bh * DD * LL + (size_t)d * LL + l0 + lq;
    *(short8*)dst = *(const short8*)&T[d][lq];
    *(short8*)(dst + 8) = *(const short8*)&T[d][lq + 8];
  }
}

// ---------------- flash attention v3: no-max softmax, 64 q/wave ----------------
// Softmax normalizer cancels => p = exp2(S) directly (S bounded; f32 lsum / bf16
// P have ample exponent range). No per-tile max, no rescale, no in-loop shuffles;
// per-lane lsum partials reduced once at the end. Waves own 64 q-rows (4 m-frags):
// K/V fragment reads amortized 2x. All 4 m's P written, ONE lgkmcnt, then all PV.
// LDS 64KB (K/V dbuf 32 + P 32), 2 blocks/CU.
__global__ __launch_bounds__(256, 2) void attn_kernel(
    const u16* __restrict__ Qh, const u16* __restrict__ Kh,
    const u16* __restrict__ Vt, u16* __restrict__ Oh) {
  __shared__ __align__(16) u16 Kl[2][64 * 64];
  __shared__ __align__(16) u16 Vl[2][64 * 64];
  __shared__ __align__(16) char Pp[4][8192];   // per-wave 8KB (4 m x 2KB)

  const int tid = threadIdx.x;
  const int lane = tid & 63, wave = tid >> 6;
  const int lr = lane & 15, lg = lane >> 4;
  const int sw = (lr & 7) * 2;
  int n = blockIdx.x;                 // 512 blocks
  int rest = n >> 3;                  // 0..63
  const int bh = (n & 7) * 16 + (rest >> 2);
  const int q0 = (rest & 3) * 256;

  const u16* Qb = Qh + (size_t)bh * LL * DD;
  const u16* Kb = Kh + (size_t)bh * LL * DD;
  const u16* Vb = Vt + (size_t)bh * DD * LL;

  short8 aq[4][2];
  #pragma unroll
  for (int m = 0; m < 4; ++m)
    #pragma unroll
    for (int s = 0; s < 2; ++s)
      aq[m][s] = *(const short8*)(Qb + (size_t)(q0 + wave * 64 + m * 16 + lr) * DD + s * 32 + lg * 8);

  f32x4 z4 = {0.f, 0.f, 0.f, 0.f};
  f32x4 oaccT[4][4];
  #pragma unroll
  for (int m = 0; m < 4; ++m)
    #pragma unroll
    for (int db = 0; db < 4; ++db) oaccT[m][db] = z4;
  float lsums[4] = {0.f, 0.f, 0.f, 0.f};

  auto stage = [&](int buf, int kt) {
    int kk0 = kt * 64;
    #pragma unroll
    for (int i = 0; i < 2; ++i) {
      int c = i * 256 + wave * 64 + lane;
      int row = c >> 3, koct = c & 7;
      int ks = koct ^ (row & 7);
      gload_lds16(Kb + (size_t)(kk0 + row) * DD + ks * 8,
                  (char*)&Kl[buf][0] + (size_t)(i * 4 + wave) * 1024);
      gload_lds16(Vb + (size_t)row * LL + kk0 + ks * 8,
                  (char*)&Vl[buf][0] + (size_t)(i * 4 + wave) * 1024);
    }
  };

  stage(0, 0);
  int cur = 0;
  char* Pw = &Pp[wave][0];
  for (int kt = 0; kt < 16; ++kt) {
    if (kt + 1 < 16) {
      stage(cur ^ 1, kt + 1);
      asm volatile("s_waitcnt vmcnt(4)" ::: "memory");
    } else {
      asm volatile("s_waitcnt vmcnt(0)" ::: "memory");
    }
    __builtin_amdgcn_s_barrier();
    __builtin_amdgcn_sched_barrier(0);

    // ---- S^T = K @ Q^T : K frags shared across all 4 m ----
    short8 ka[2][4];
    #pragma unroll
    for (int s = 0; s < 2; ++s)
      #pragma unroll
      for (int kb = 0; kb < 4; ++kb) {
        int key = kb * 16 + lr;
        int dct = s * 4 + lg;
        ka[s][kb] = *(const short8*)((const char*)&Kl[cur][0] + (size_t)key * 128 + ((dct ^ (key & 7)) << 4));
      }
    f32x4 ps[4][4];
    #pragma unroll
    for (int m = 0; m < 4; ++m)
      #pragma unroll
      for (int kb = 0; kb < 4; ++kb) ps[m][kb] = z4;
    __builtin_amdgcn_s_setprio(1);
    #pragma unroll
    for (int s = 0; s < 2; ++s)
      #pragma unroll
      for (int kb = 0; kb < 4; ++kb)
        #pragma unroll
        for (int m = 0; m < 4; ++m)
          ps[m][kb] = __builtin_amdgcn_mfma_f32_16x16x32_bf16(ka[s][kb], aq[m][s], ps[m][kb], 0, 0, 0);
    __builtin_amdgcn_s_setprio(0);

    // ---- no-max softmax: p = exp2(S); lane-local lsum partials; write P ----
    #pragma unroll
    for (int m = 0; m < 4; ++m) {
      #pragma unroll
      for (int kb = 0; kb < 4; ++kb) {
        float p0, p1, p2, p3;
        asm("v_exp_f32 %0, %1" : "=v"(p0) : "v"(ps[m][kb][0]));
        asm("v_exp_f32 %0, %1" : "=v"(p1) : "v"(ps[m][kb][1]));
        asm("v_exp_f32 %0, %1" : "=v"(p2) : "v"(ps[m][kb][2]));
        asm("v_exp_f32 %0, %1" : "=v"(p3) : "v"(ps[m][kb][3]));
        lsums[m] += (p0 + p1) + (p2 + p3);
        unsigned lo, hi;
        asm("v_cvt_pk_bf16_f32 %0, %1, %2" : "=v"(lo) : "v"(p0), "v"(p1));
        asm("v_cvt_pk_bf16_f32 %0, %1, %2" : "=v"(hi) : "v"(p2), "v"(p3));
        uint2 w; w.x = lo; w.y = hi;
        *(uint2*)(Pw + m * 2048 + lr * 128 + ((((kb * 4 + lg) ^ sw)) << 3)) = w;
      }
    }

    // ---- V fragments (shared across all 4 m) ----
    short8 bv[2][4];
    #pragma unroll
    for (int s = 0; s < 2; ++s)
      #pragma unroll
      for (int db = 0; db < 4; ++db) {
        int d = db * 16 + lr;
        int kct = s * 4 + lg;
        bv[s][db] = *(const short8*)((const char*)&Vl[cur][0] + (size_t)d * 128 + ((kct ^ (d & 7)) << 4));
      }

    asm volatile("s_waitcnt lgkmcnt(0)" ::: "memory");
    __builtin_amdgcn_sched_barrier(0);

    // ---- O^T += V^T @ P for all m ----
    __builtin_amdgcn_s_setprio(1);
    #pragma unroll
    for (int m = 0; m < 4; ++m) {
      #pragma unroll
      for (int s = 0; s < 2; ++s) {
        int val0 = s * 8 + lg * 2;
        uint4 pw = *(const uint4*)(Pw + m * 2048 + lr * 128 + (((val0 ^ sw)) << 3));
        short8 ap = __builtin_bit_cast(short8, pw);
        #pragma unroll
        for (int db = 0; db < 4; ++db)
          oaccT[m][db] = __builtin_amdgcn_mfma_f32_16x16x32_bf16(bv[s][db], ap, oaccT[m][db], 0, 0, 0);
      }
    }
    __builtin_amdgcn_s_setprio(0);

    __builtin_amdgcn_s_barrier();
    cur ^= 1;
  }

  // epilogue: reduce lsum partials across the lg-group once, scale, store
  int b = bh >> 3, h = bh & 7;
  #pragma unroll
  for (int m = 0; m < 4; ++m) {
    float v = lsums[m];
    v += __shfl_xor(v, 16);
    v += __shfl_xor(v, 32);
    float inv = 1.0f / v;
    int q = q0 + wave * 64 + m * 16 + lr;
    #pragma unroll
    for (int db = 0; db < 4; ++db) {
      int d0 = db * 16 + lg * 4;
      short4v o;
      #pragma unroll
      for (int r = 0; r < 4; ++r) o[r] = f2bf(oaccT[m][db][r] * inv);
      *(short4v*)&Oh[(size_t)(b * LL + q) * CC + h * 64 + d0] = o;
    }
  }
}

// ---------------- output projection + residual ----------------
__global__ __launch_bounds__(256) void out_gemm_kernel(
    const u16* __restrict__ Oh, const u16* __restrict__ Wo_bf,
    const float* __restrict__ bo, const float* __restrict__ query,
    float* __restrict__ out) {
  __shared__ __align__(16) u16 Alds[2 * BM * BK];
  __shared__ __align__(16) u16 Blds[2 * BN * BK];
  int m0 = blockIdx.x * BM, n0 = blockIdx.y * BN;
  f32x4 acc[4][4];
  f32x4 z4 = {0.f, 0.f, 0.f, 0.f};
  #pragma unroll
  for (int m = 0; m < 4; ++m)
    #pragma unroll
    for (int n = 0; n < 4; ++n) acc[m][n] = z4;

  gemm_mainloop<CC>(Oh, Wo_bf, m0, n0, Alds, Blds, acc);

  const int lane = threadIdx.x & 63, wave = threadIdx.x >> 6;
  const int wr = wave >> 1, wc = wave & 1;
  const int lr = lane & 15, lg = lane >> 4;
  #pragma unroll
  for (int m = 0; m < 4; ++m) {
    int rowb = m0 + wr * 64 + m * 16 + lg * 4;
    #pragma unroll
    for (int n = 0; n < 4; ++n) {
      int col = n0 + wc * 64 + n * 16 + lr;
      float bias = bo[col];
      #pragma unroll
      for (int r = 0; r < 4; ++r) {
        int rw = rowb + r;
        size_t idx = (size_t)rw * CC + col;
        out[idx] = acc[m][n][r] + bias + query[idx];
      }
    }
  }
}

// ---------------- launcher ----------------
extern "C" void kernel_launch(void* const* d_in, const int* in_sizes, int n_in,
                              void* d_out, int out_size, void* d_ws, size_t ws_size,
                              hipStream_t stream) {
  (void)in_sizes; (void)n_in; (void)out_size;
  const float* query = (const float*)d_in[0];
  const float* qpos  = (const float*)d_in[1];
  const float* Wqc = (const float*)d_in[2];
  const float* bqc = (const float*)d_in[3];
  const float* Wqp = (const float*)d_in[4];
  const float* bqp = (const float*)d_in[5];
  const float* Wkc = (const float*)d_in[6];
  const float* bkc = (const float*)d_in[7];
  const float* Wkp = (const float*)d_in[8];
  const float* bkp = (const float*)d_in[9];
  const float* Wv  = (const float*)d_in[10];
  const float* bv  = (const float*)d_in[11];
  const float* Wo  = (const float*)d_in[12];
  const float* bo  = (const float*)d_in[13];

  char* ws = (char*)d_ws;
  if (ws_size < WS_END) return;

  u16*   Xcat     = (u16*)(ws + WS_XCAT);
  u16*   Wcat     = (u16*)(ws + WS_WCAT);
  u16*   Wo_bf    = (u16*)(ws + WS_WO);
  float* bias_cat = (float*)(ws + WS_BIAS);
  u16*   Qh       = (u16*)(ws + WS_QH);
  u16*   Kh       = (u16*)(ws + WS_KH);
  u16*   Vh       = (u16*)(ws + WS_VH);
  u16*   Oh       = (u16*)(ws + WS_OH);
  u16*   Vtr      = (u16*)(ws + WS_VT);   // aliases Xcat (dead after proj)
  float* out      = (float*)d_out;

  pack_x_kernel<<<dim3(8192), dim3(256), 0, stream>>>(query, qpos, Xcat);
  pack_w_kernel<<<dim3(896), dim3(256), 0, stream>>>(Wqc, Wqp, Wkc, Wkp, Wv, Wo,
                                                     bqc, bqp, bkc, bkp, bv,
                                                     Wcat, Wo_bf, bias_cat);
  proj_gemm_kernel<<<dim3((MROWS / 256) * (NPROJ / 256)), dim3(512), 0, stream>>>(
      Xcat, Wcat, bias_cat, Qh, Kh, Vh);
  vtrans_kernel<<<dim3(LL / 64, BB * HH), dim3(256), 0, stream>>>(Vh, Vtr);
  attn_kernel<<<dim3(512), dim3(256), 0, stream>>>(Qh, Kh, Vtr, Oh);
  out_gemm_kernel<<<dim3(MROWS / BM, CC / BN), dim3(256), 0, stream>>>(
      Oh, Wo_bf, bo, query, out);
}

// Round 9
// 168.808 us; speedup vs baseline: 1.1817x; 1.0049x over previous
//
#include <hip/hip_runtime.h>

typedef __attribute__((ext_vector_type(8))) short short8;
typedef __attribute__((ext_vector_type(4))) short short4v;
typedef __attribute__((ext_vector_type(4))) float f32x4;
typedef unsigned short u16;

#define QSCALE 0.18033688011112042f   /* 0.125 * log2(e): softmax done in exp2 domain */

#define BB 16
#define LL 1024
#define CC 512
#define HH 8
#define DD 64
#define MROWS (BB*LL)      /* 16384 */
#define KPROJ 1024
#define NPROJ 1536

#define BM 128
#define BN 128
#define BK 32

// workspace offsets (bytes). Vt aliases Xcat (Xcat dead after proj_gemm).
#define WS_XCAT   0ull
#define WS_WCAT   (WS_XCAT + (size_t)MROWS*KPROJ*2)
#define WS_WO     (WS_WCAT + (size_t)NPROJ*KPROJ*2)
#define WS_BIAS   (WS_WO   + (size_t)CC*CC*2)
#define WS_QH     (WS_BIAS + 8192)
#define WS_KH     (WS_QH + (size_t)MROWS*CC*2)
#define WS_VH     (WS_KH + (size_t)MROWS*CC*2)
#define WS_OH     (WS_VH + (size_t)MROWS*CC*2)
#define WS_END    (WS_OH + (size_t)MROWS*CC*2)
#define WS_VT     WS_XCAT

__device__ inline short f2bf(float f) {
  unsigned u = __builtin_bit_cast(unsigned, f);
  u = (u + 0x7FFFu + ((u >> 16) & 1u)) >> 16;
  return (short)u;
}

__device__ inline short8 pack8(const float* src) {
  float4 a = ((const float4*)src)[0];
  float4 b = ((const float4*)src)[1];
  short8 v;
  v[0]=f2bf(a.x); v[1]=f2bf(a.y); v[2]=f2bf(a.z); v[3]=f2bf(a.w);
  v[4]=f2bf(b.x); v[5]=f2bf(b.y); v[6]=f2bf(b.z); v[7]=f2bf(b.w);
  return v;
}

__device__ inline void gload_lds16(const u16* g, char* lds_byte) {
  __builtin_amdgcn_global_load_lds(
      (const __attribute__((address_space(1))) unsigned int*)g,
      (__attribute__((address_space(3))) unsigned int*)lds_byte,
      16, 0, 0);
}

// ---------------- pack kernels ----------------

__global__ __launch_bounds__(256) void pack_x_kernel(
    const float* __restrict__ q, const float* __restrict__ qp, u16* __restrict__ xcat) {
  int o = blockIdx.x * 256 + threadIdx.x;
  int row = o >> 7;
  int kk  = (o & 127) << 3;
  const float* src = (kk < 512) ? (q + (size_t)row * 512 + kk)
                                : (qp + (size_t)row * 512 + (kk - 512));
  short8 v = pack8(src);
  *(short8*)(xcat + (size_t)row * KPROJ + kk) = v;
}

__global__ __launch_bounds__(256) void pack_w_kernel(
    const float* __restrict__ Wqc, const float* __restrict__ Wqp,
    const float* __restrict__ Wkc, const float* __restrict__ Wkp,
    const float* __restrict__ Wv,  const float* __restrict__ Wo,
    const float* __restrict__ bqc, const float* __restrict__ bqp,
    const float* __restrict__ bkc, const float* __restrict__ bkp,
    const float* __restrict__ bv,
    u16* __restrict__ wcat, u16* __restrict__ wo_bf, float* __restrict__ bias_cat) {
  int o = blockIdx.x * 256 + threadIdx.x;
  if (o < 196608) {
    int j = o >> 7;
    int kk = (o & 127) << 3;
    const float* src = nullptr;
    if (j < 512)        src = (kk < 512) ? Wqc + (size_t)j * 512 + kk : Wqp + (size_t)j * 512 + (kk - 512);
    else if (j < 1024) { int jj = j - 512;  src = (kk < 512) ? Wkc + (size_t)jj * 512 + kk : Wkp + (size_t)jj * 512 + (kk - 512); }
    else               { int jj = j - 1024; src = (kk < 512) ? Wv  + (size_t)jj * 512 + kk : nullptr; }
    short8 v = {0,0,0,0,0,0,0,0};
    if (src) v = pack8(src);
    *(short8*)(wcat + (size_t)j * KPROJ + kk) = v;
  } else if (o < 229376) {
    int o2 = o - 196608;
    int j = o2 >> 6;
    int kk = (o2 & 63) << 3;
    short8 v = pack8(Wo + (size_t)j * 512 + kk);
    *(short8*)(wo_bf + (size_t)j * 512 + kk) = v;
  }
  if (o < 1536) {
    float v;
    if (o < 512)       v = bqc[o] + bqp[o];
    else if (o < 1024) v = bkc[o - 512] + bkp[o - 512];
    else               v = bv[o - 1024];
    bias_cat[o] = v;
  }
}

// ---------------- legacy 128x128 GEMM core (out_gemm) ----------------
template <int KDIM>
__device__ inline void gemm_mainloop(const u16* __restrict__ A, const u16* __restrict__ Bw,
                                     int m0, int n0,
                                     u16* Alds, u16* Blds,
                                     f32x4 (&acc)[4][4]) {
  const int tid = threadIdx.x;
  const int lane = tid & 63, wave = tid >> 6;
  const int wr = wave >> 1, wc = wave & 1;
  const int lr = lane & 15, lg = lane >> 4;

  auto stage = [&](int buf, int t) {
    int k0 = t * BK;
    #pragma unroll
    for (int i = 0; i < 2; ++i) {
      int c = (i * 4 + wave) * 64 + lane;
      int row = c >> 2, koct = c & 3;
      char* ldsbaseA = (char*)Alds + (size_t)buf * (BM * BK * 2) + (size_t)(i * 4 + wave) * 1024;
      char* ldsbaseB = (char*)Blds + (size_t)buf * (BN * BK * 2) + (size_t)(i * 4 + wave) * 1024;
      gload_lds16(A  + (size_t)(m0 + row) * KDIM + k0 + koct * 8, ldsbaseA);
      gload_lds16(Bw + (size_t)(n0 + row) * KDIM + k0 + koct * 8, ldsbaseB);
    }
  };

  stage(0, 0);
  constexpr int NT = KDIM / BK;
  int cur = 0;
  for (int t = 0; t < NT; ++t) {
    __syncthreads();
    if (t + 1 < NT) stage(cur ^ 1, t + 1);
    const u16* Ab = Alds + (size_t)cur * (BM * BK);
    const u16* Bb = Blds + (size_t)cur * (BN * BK);
    short8 af[4], bfr[4];
    #pragma unroll
    for (int m = 0; m < 4; ++m)
      af[m] = *(const short8*)(Ab + (size_t)(wr * 64 + m * 16 + lr) * BK + lg * 8);
    #pragma unroll
    for (int n = 0; n < 4; ++n)
      bfr[n] = *(const short8*)(Bb + (size_t)(wc * 64 + n * 16 + lr) * BK + lg * 8);
    #pragma unroll
    for (int m = 0; m < 4; ++m)
      #pragma unroll
      for (int n = 0; n < 4; ++n)
        acc[m][n] = __builtin_amdgcn_mfma_f32_16x16x32_bf16(af[m], bfr[n], acc[m][n], 0, 0, 0);
    cur ^= 1;
  }
}

// ---------------- projection GEMM: 256x256 tile, BK=64, 8 waves, 2 superphases ----------------
// 2 barriers per K-tile (was 8). Stage groups: G1 = B-all + A-lo (6 instr, read at
// next tile sp0), G2 = A-hi (2 instr, read at next tile sp1). vmcnt retires in issue
// order: end-sp0 vmcnt(6) retires prev G2; end-sp1 vmcnt(2) retires G1. Every group
// has >= 1 superphase of latency cover; every drain precedes the barrier that
// precedes its first cross-wave read.
__global__ __launch_bounds__(512, 2) void proj_gemm_kernel(
    const u16* __restrict__ Xcat, const u16* __restrict__ Wcat,
    const float* __restrict__ bias_cat,
    u16* __restrict__ Qh, u16* __restrict__ Kh, u16* __restrict__ Vh) {
  __shared__ __align__(16) u16 lds[2 * 32768];   // 128 KB

  // bijective XCD swizzle (384 blocks, 384 % 8 == 0)
  int id0 = blockIdx.x;
  int swz = (id0 & 7) * 48 + (id0 >> 3);
  int bx = swz / 6, by = swz % 6;
  const int m0 = bx * 256, n0 = by * 256;

  const int tid = threadIdx.x;
  const int lane = tid & 63, wave = tid >> 6;
  const int wr = wave >> 2, wc = wave & 3;
  const int lr = lane & 15, lg = lane >> 4;

  // stage one 8KB half-unit: unit u in {0:A rows 0-127, 1:A rows 128-255,
  // 2:B rows 0-127, 3:B rows 128-255}; half i covers unit-rows i*64..i*64+63.
  auto stage_half = [&](int buf, int u, int i, int k0) {
    const u16* base = (u < 2) ? (Xcat + (size_t)(m0 + u * 128) * KPROJ + k0)
                              : (Wcat + (size_t)(n0 + (u - 2) * 128) * KPROJ + k0);
    int s = i * 512 + tid;
    int row = s >> 3, col = s & 7;
    int colp = col ^ (row & 7);              // inverse swizzle on SOURCE, linear dest
    gload_lds16(base + (size_t)row * KPROJ + colp * 8,
                (char*)lds + ((size_t)buf * 32768 + (size_t)u * 8192) * 2
                           + (size_t)(i * 512 + wave * 64) * 16);
  };

  auto rdW = [&](int buf, int nf, int ks) {
    int rowl = (wc & 1) * 64 + nf * 16 + lr;
    int chunk = (ks * 4 + lg) ^ (rowl & 7);
    return *(const short8*)(lds + (size_t)buf * 32768 + (size_t)(2 + (wc >> 1)) * 8192
                            + (size_t)rowl * 64 + chunk * 8);
  };
  auto rdX = [&](int buf, int mf, int ks) {
    int rowl = mf * 16 + lr;
    int chunk = (ks * 4 + lg) ^ (rowl & 7);
    return *(const short8*)(lds + (size_t)buf * 32768 + (size_t)wr * 8192
                            + (size_t)rowl * 64 + chunk * 8);
  };

  f32x4 acc[8][4];
  f32x4 z4 = {0.f, 0.f, 0.f, 0.f};
  #pragma unroll
  for (int mf = 0; mf < 8; ++mf)
    #pragma unroll
    for (int nf = 0; nf < 4; ++nf) acc[mf][nf] = z4;

  // prologue: stage K-tile 0 into buf 0, drain, barrier
  #pragma unroll
  for (int u = 0; u < 4; ++u) {
    stage_half(0, u, 0, 0);
    stage_half(0, u, 1, 0);
  }
  asm volatile("s_waitcnt vmcnt(0)" ::: "memory");
  __builtin_amdgcn_s_barrier();
  __builtin_amdgcn_sched_barrier(0);

  short8 wfr[4][2];
  constexpr int NT = KPROJ / 64;   // 16 K-tiles
  for (int kt = 0; kt < NT; ++kt) {
    const int b = kt & 1;
    const bool pf = (kt + 1 < NT);
    const int k1 = (kt + 1) * 64;

    // ---- superphase 0: B-frags + A mf0-3; stage G1 (B-all + A-lo); 32 MFMA ----
    #pragma unroll
    for (int nf = 0; nf < 4; ++nf)
      #pragma unroll
      for (int ks = 0; ks < 2; ++ks) wfr[nf][ks] = rdW(b, nf, ks);
    short8 xf[4][2];
    #pragma unroll
    for (int mf = 0; mf < 4; ++mf)
      #pragma unroll
      for (int ks = 0; ks < 2; ++ks) xf[mf][ks] = rdX(b, mf, ks);
    if (pf) {
      stage_half(b ^ 1, 2, 0, k1); stage_half(b ^ 1, 2, 1, k1);
      stage_half(b ^ 1, 3, 0, k1); stage_half(b ^ 1, 3, 1, k1);
      stage_half(b ^ 1, 0, 0, k1); stage_half(b ^ 1, 1, 0, k1);
    }
    __builtin_amdgcn_s_setprio(1);
    #pragma unroll
    for (int mf = 0; mf < 4; ++mf)
      #pragma unroll
      for (int nf = 0; nf < 4; ++nf)
        #pragma unroll
        for (int ks = 0; ks < 2; ++ks)
          acc[mf][nf] = __builtin_amdgcn_mfma_f32_16x16x32_bf16(
              wfr[nf][ks], xf[mf][ks], acc[mf][nf], 0, 0, 0);
    __builtin_amdgcn_s_setprio(0);
    if (pf) asm volatile("s_waitcnt vmcnt(6)" ::: "memory");   // retire prev G2 (A-hi)
    else    asm volatile("s_waitcnt vmcnt(0)" ::: "memory");
    __builtin_amdgcn_s_barrier();
    __builtin_amdgcn_sched_barrier(0);

    // ---- superphase 1: A mf4-7; stage G2 (A-hi); 32 MFMA ----
    #pragma unroll
    for (int mf = 0; mf < 4; ++mf)
      #pragma unroll
      for (int ks = 0; ks < 2; ++ks) xf[mf][ks] = rdX(b, 4 + mf, ks);
    if (pf) {
      stage_half(b ^ 1, 0, 1, k1); stage_half(b ^ 1, 1, 1, k1);
    }
    __builtin_amdgcn_s_setprio(1);
    #pragma unroll
    for (int mf = 0; mf < 4; ++mf)
      #pragma unroll
      for (int nf = 0; nf < 4; ++nf)
        #pragma unroll
        for (int ks = 0; ks < 2; ++ks)
          acc[4 + mf][nf] = __builtin_amdgcn_mfma_f32_16x16x32_bf16(
              wfr[nf][ks], xf[mf][ks], acc[4 + mf][nf], 0, 0, 0);
    __builtin_amdgcn_s_setprio(0);
    if (pf) asm volatile("s_waitcnt vmcnt(2)" ::: "memory");   // retire G1 (B + A-lo)
    else    asm volatile("s_waitcnt vmcnt(0)" ::: "memory");
    __builtin_amdgcn_s_barrier();
    __builtin_amdgcn_sched_barrier(0);
  }

  const int cbase = n0 + wc * 64 + lg * 4;
  #pragma unroll
  for (int mf = 0; mf < 8; ++mf) {
    int lglob = m0 + wr * 128 + mf * 16 + lr;
    int bidx = lglob >> 10, lrow = lglob & 1023;
    #pragma unroll
    for (int nf = 0; nf < 4; ++nf) {
      int c = cbase + nf * 16;
      float4 bb = *(const float4*)&bias_cat[c];
      int sec = c >> 9, cj = c & 511;
      int h = cj >> 6, d0 = cj & 63;
      size_t idx = ((size_t)(bidx * HH + h) * LL + lrow) * DD + d0;
      float v0 = acc[mf][nf][0] + bb.x;
      float v1 = acc[mf][nf][1] + bb.y;
      float v2 = acc[mf][nf][2] + bb.z;
      float v3 = acc[mf][nf][3] + bb.w;
      if (sec == 0) { v0 *= QSCALE; v1 *= QSCALE; v2 *= QSCALE; v3 *= QSCALE; }
      short4v o;
      o[0] = f2bf(v0); o[1] = f2bf(v1); o[2] = f2bf(v2); o[3] = f2bf(v3);
      u16* dst = (sec == 0) ? Qh : (sec == 1) ? Kh : Vh;
      *(short4v*)&dst[idx] = o;
    }
  }
}

// ---------------- V transpose: Vh[bh][l][d] -> Vt[bh][d][l] ----------------
__global__ __launch_bounds__(256) void vtrans_kernel(
    const u16* __restrict__ Vh, u16* __restrict__ Vt) {
  __shared__ u16 T[64][72];
  int bh = blockIdx.y;
  int l0 = blockIdx.x * 64;
  int t = threadIdx.x;
  const u16* src = Vh + (size_t)bh * LL * DD;
  {
    int l = t >> 2, dq = (t & 3) * 16;
    short8 v0 = *(const short8*)(src + (size_t)(l0 + l) * DD + dq);
    short8 v1 = *(const short8*)(src + (size_t)(l0 + l) * DD + dq + 8);
    #pragma unroll
    for (int j = 0; j < 8; ++j) T[dq + j][l] = (u16)v0[j];
    #pragma unroll
    for (int j = 0; j < 8; ++j) T[dq + 8 + j][l] = (u16)v1[j];
  }
  __syncthreads();
  {
    int d = t >> 2, lq = (t & 3) * 16;
    u16* dst = Vt + (size_t)bh * DD * LL + (size_t)d * LL + l0 + lq;
    *(short8*)dst = *(const short8*)&T[d][lq];
    *(short8*)(dst + 8) = *(const short8*)&T[d][lq + 8];
  }
}

// ---------------- flash attention v3: no-max softmax, 64 q/wave ----------------
__global__ __launch_bounds__(256, 2) void attn_kernel(
    const u16* __restrict__ Qh, const u16* __restrict__ Kh,
    const u16* __restrict__ Vt, u16* __restrict__ Oh) {
  __shared__ __align__(16) u16 Kl[2][64 * 64];
  __shared__ __align__(16) u16 Vl[2][64 * 64];
  __shared__ __align__(16) char Pp[4][8192];   // per-wave 8KB (4 m x 2KB)

  const int tid = threadIdx.x;
  const int lane = tid & 63, wave = tid >> 6;
  const int lr = lane & 15, lg = lane >> 4;
  const int sw = (lr & 7) * 2;
  int n = blockIdx.x;                 // 512 blocks
  int rest = n >> 3;                  // 0..63
  const int bh = (n & 7) * 16 + (rest >> 2);
  const int q0 = (rest & 3) * 256;

  const u16* Qb = Qh + (size_t)bh * LL * DD;
  const u16* Kb = Kh + (size_t)bh * LL * DD;
  const u16* Vb = Vt + (size_t)bh * DD * LL;

  short8 aq[4][2];
  #pragma unroll
  for (int m = 0; m < 4; ++m)
    #pragma unroll
    for (int s = 0; s < 2; ++s)
      aq[m][s] = *(const short8*)(Qb + (size_t)(q0 + wave * 64 + m * 16 + lr) * DD + s * 32 + lg * 8);

  f32x4 z4 = {0.f, 0.f, 0.f, 0.f};
  f32x4 oaccT[4][4];
  #pragma unroll
  for (int m = 0; m < 4; ++m)
    #pragma unroll
    for (int db = 0; db < 4; ++db) oaccT[m][db] = z4;
  float lsums[4] = {0.f, 0.f, 0.f, 0.f};

  auto stage = [&](int buf, int kt) {
    int kk0 = kt * 64;
    #pragma unroll
    for (int i = 0; i < 2; ++i) {
      int c = i * 256 + wave * 64 + lane;
      int row = c >> 3, koct = c & 7;
      int ks = koct ^ (row & 7);
      gload_lds16(Kb + (size_t)(kk0 + row) * DD + ks * 8,
                  (char*)&Kl[buf][0] + (size_t)(i * 4 + wave) * 1024);
      gload_lds16(Vb + (size_t)row * LL + kk0 + ks * 8,
                  (char*)&Vl[buf][0] + (size_t)(i * 4 + wave) * 1024);
    }
  };

  stage(0, 0);
  int cur = 0;
  char* Pw = &Pp[wave][0];
  for (int kt = 0; kt < 16; ++kt) {
    if (kt + 1 < 16) {
      stage(cur ^ 1, kt + 1);
      asm volatile("s_waitcnt vmcnt(4)" ::: "memory");
    } else {
      asm volatile("s_waitcnt vmcnt(0)" ::: "memory");
    }
    __builtin_amdgcn_s_barrier();
    __builtin_amdgcn_sched_barrier(0);

    // ---- S^T = K @ Q^T : K frags shared across all 4 m ----
    short8 ka[2][4];
    #pragma unroll
    for (int s = 0; s < 2; ++s)
      #pragma unroll
      for (int kb = 0; kb < 4; ++kb) {
        int key = kb * 16 + lr;
        int dct = s * 4 + lg;
        ka[s][kb] = *(const short8*)((const char*)&Kl[cur][0] + (size_t)key * 128 + ((dct ^ (key & 7)) << 4));
      }
    f32x4 ps[4][4];
    #pragma unroll
    for (int m = 0; m < 4; ++m)
      #pragma unroll
      for (int kb = 0; kb < 4; ++kb) ps[m][kb] = z4;
    __builtin_amdgcn_s_setprio(1);
    #pragma unroll
    for (int s = 0; s < 2; ++s)
      #pragma unroll
      for (int kb = 0; kb < 4; ++kb)
        #pragma unroll
        for (int m = 0; m < 4; ++m)
          ps[m][kb] = __builtin_amdgcn_mfma_f32_16x16x32_bf16(ka[s][kb], aq[m][s], ps[m][kb], 0, 0, 0);
    __builtin_amdgcn_s_setprio(0);

    // ---- no-max softmax: p = exp2(S); lane-local lsum partials; write P ----
    #pragma unroll
    for (int m = 0; m < 4; ++m) {
      #pragma unroll
      for (int kb = 0; kb < 4; ++kb) {
        float p0, p1, p2, p3;
        asm("v_exp_f32 %0, %1" : "=v"(p0) : "v"(ps[m][kb][0]));
        asm("v_exp_f32 %0, %1" : "=v"(p1) : "v"(ps[m][kb][1]));
        asm("v_exp_f32 %0, %1" : "=v"(p2) : "v"(ps[m][kb][2]));
        asm("v_exp_f32 %0, %1" : "=v"(p3) : "v"(ps[m][kb][3]));
        lsums[m] += (p0 + p1) + (p2 + p3);
        unsigned lo, hi;
        asm("v_cvt_pk_bf16_f32 %0, %1, %2" : "=v"(lo) : "v"(p0), "v"(p1));
        asm("v_cvt_pk_bf16_f32 %0, %1, %2" : "=v"(hi) : "v"(p2), "v"(p3));
        uint2 w; w.x = lo; w.y = hi;
        *(uint2*)(Pw + m * 2048 + lr * 128 + ((((kb * 4 + lg) ^ sw)) << 3)) = w;
      }
    }

    // ---- V fragments (shared across all 4 m) ----
    short8 bv[2][4];
    #pragma unroll
    for (int s = 0; s < 2; ++s)
      #pragma unroll
      for (int db = 0; db < 4; ++db) {
        int d = db * 16 + lr;
        int kct = s * 4 + lg;
        bv[s][db] = *(const short8*)((const char*)&Vl[cur][0] + (size_t)d * 128 + ((kct ^ (d & 7)) << 4));
      }

    asm volatile("s_waitcnt lgkmcnt(0)" ::: "memory");
    __builtin_amdgcn_sched_barrier(0);

    // ---- O^T += V^T @ P for all m ----
    __builtin_amdgcn_s_setprio(1);
    #pragma unroll
    for (int m = 0; m < 4; ++m) {
      #pragma unroll
      for (int s = 0; s < 2; ++s) {
        int val0 = s * 8 + lg * 2;
        uint4 pw = *(const uint4*)(Pw + m * 2048 + lr * 128 + (((val0 ^ sw)) << 3));
        short8 ap = __builtin_bit_cast(short8, pw);
        #pragma unroll
        for (int db = 0; db < 4; ++db)
          oaccT[m][db] = __builtin_amdgcn_mfma_f32_16x16x32_bf16(bv[s][db], ap, oaccT[m][db], 0, 0, 0);
      }
    }
    __builtin_amdgcn_s_setprio(0);

    __builtin_amdgcn_s_barrier();
    cur ^= 1;
  }

  // epilogue: reduce lsum partials across the lg-group once, scale, store
  int b = bh >> 3, h = bh & 7;
  #pragma unroll
  for (int m = 0; m < 4; ++m) {
    float v = lsums[m];
    v += __shfl_xor(v, 16);
    v += __shfl_xor(v, 32);
    float inv = 1.0f / v;
    int q = q0 + wave * 64 + m * 16 + lr;
    #pragma unroll
    for (int db = 0; db < 4; ++db) {
      int d0 = db * 16 + lg * 4;
      short4v o;
      #pragma unroll
      for (int r = 0; r < 4; ++r) o[r] = f2bf(oaccT[m][db][r] * inv);
      *(short4v*)&Oh[(size_t)(b * LL + q) * CC + h * 64 + d0] = o;
    }
  }
}

// ---------------- output projection + residual ----------------
__global__ __launch_bounds__(256) void out_gemm_kernel(
    const u16* __restrict__ Oh, const u16* __restrict__ Wo_bf,
    const float* __restrict__ bo, const float* __restrict__ query,
    float* __restrict__ out) {
  __shared__ __align__(16) u16 Alds[2 * BM * BK];
  __shared__ __align__(16) u16 Blds[2 * BN * BK];
  int m0 = blockIdx.x * BM, n0 = blockIdx.y * BN;
  f32x4 acc[4][4];
  f32x4 z4 = {0.f, 0.f, 0.f, 0.f};
  #pragma unroll
  for (int m = 0; m < 4; ++m)
    #pragma unroll
    for (int n = 0; n < 4; ++n) acc[m][n] = z4;

  gemm_mainloop<CC>(Oh, Wo_bf, m0, n0, Alds, Blds, acc);

  const int lane = threadIdx.x & 63, wave = threadIdx.x >> 6;
  const int wr = wave >> 1, wc = wave & 1;
  const int lr = lane & 15, lg = lane >> 4;
  #pragma unroll
  for (int m = 0; m < 4; ++m) {
    int rowb = m0 + wr * 64 + m * 16 + lg * 4;
    #pragma unroll
    for (int n = 0; n < 4; ++n) {
      int col = n0 + wc * 64 + n * 16 + lr;
      float bias = bo[col];
      #pragma unroll
      for (int r = 0; r < 4; ++r) {
        int rw = rowb + r;
        size_t idx = (size_t)rw * CC + col;
        out[idx] = acc[m][n][r] + bias + query[idx];
      }
    }
  }
}

// ---------------- launcher ----------------
extern "C" void kernel_launch(void* const* d_in, const int* in_sizes, int n_in,
                              void* d_out, int out_size, void* d_ws, size_t ws_size,
                              hipStream_t stream) {
  (void)in_sizes; (void)n_in; (void)out_size;
  const float* query = (const float*)d_in[0];
  const float* qpos  = (const float*)d_in[1];
  const float* Wqc = (const float*)d_in[2];
  const float* bqc = (const float*)d_in[3];
  const float* Wqp = (const float*)d_in[4];
  const float* bqp = (const float*)d_in[5];
  const float* Wkc = (const float*)d_in[6];
  const float* bkc = (const float*)d_in[7];
  const float* Wkp = (const float*)d_in[8];
  const float* bkp = (const float*)d_in[9];
  const float* Wv  = (const float*)d_in[10];
  const float* bv  = (const float*)d_in[11];
  const float* Wo  = (const float*)d_in[12];
  const float* bo  = (const float*)d_in[13];

  char* ws = (char*)d_ws;
  if (ws_size < WS_END) return;

  u16*   Xcat     = (u16*)(ws + WS_XCAT);
  u16*   Wcat     = (u16*)(ws + WS_WCAT);
  u16*   Wo_bf    = (u16*)(ws + WS_WO);
  float* bias_cat = (float*)(ws + WS_BIAS);
  u16*   Qh       = (u16*)(ws + WS_QH);
  u16*   Kh       = (u16*)(ws + WS_KH);
  u16*   Vh       = (u16*)(ws + WS_VH);
  u16*   Oh       = (u16*)(ws + WS_OH);
  u16*   Vtr      = (u16*)(ws + WS_VT);   // aliases Xcat (dead after proj)
  float* out      = (float*)d_out;

  pack_x_kernel<<<dim3(8192), dim3(256), 0, stream>>>(query, qpos, Xcat);
  pack_w_kernel<<<dim3(896), dim3(256), 0, stream>>>(Wqc, Wqp, Wkc, Wkp, Wv, Wo,
                                                     bqc, bqp, bkc, bkp, bv,
                                                     Wcat, Wo_bf, bias_cat);
  proj_gemm_kernel<<<dim3((MROWS / 256) * (NPROJ / 256)), dim3(512), 0, stream>>>(
      Xcat, Wcat, bias_cat, Qh, Kh, Vh);
  vtrans_kernel<<<dim3(LL / 64, BB * HH), dim3(256), 0, stream>>>(Vh, Vtr);
  attn_kernel<<<dim3(512), dim3(256), 0, stream>>>(Qh, Kh, Vtr, Oh);
  out_gemm_kernel<<<dim3(MROWS / BM, CC / BN), dim3(256), 0, stream>>>(
      Oh, Wo_bf, bo, query, out);
}

// Round 10
// 159.387 us; speedup vs baseline: 1.2516x; 1.0591x over previous
//
#include <hip/hip_runtime.h>

typedef __attribute__((ext_vector_type(8))) short short8;
typedef __attribute__((ext_vector_type(4))) short short4v;
typedef __attribute__((ext_vector_type(4))) float f32x4;
typedef unsigned short u16;

#define QSCALE 0.18033688011112042f   /* 0.125 * log2(e): softmax done in exp2 domain */

#define BB 16
#define LL 1024
#define CC 512
#define HH 8
#define DD 64
#define MROWS (BB*LL)      /* 16384 */
#define KPROJ 1024
#define NPROJ 1536

// workspace offsets (bytes). Vt aliases Xcat (Xcat dead after proj_gemm).
#define WS_XCAT   0ull
#define WS_WCAT   (WS_XCAT + (size_t)MROWS*KPROJ*2)
#define WS_WO     (WS_WCAT + (size_t)NPROJ*KPROJ*2)
#define WS_BIAS   (WS_WO   + (size_t)CC*CC*2)
#define WS_QH     (WS_BIAS + 8192)
#define WS_KH     (WS_QH + (size_t)MROWS*CC*2)
#define WS_VH     (WS_KH + (size_t)MROWS*CC*2)
#define WS_OH     (WS_VH + (size_t)MROWS*CC*2)
#define WS_END    (WS_OH + (size_t)MROWS*CC*2)
#define WS_VT     WS_XCAT

__device__ inline short f2bf(float f) {
  unsigned u = __builtin_bit_cast(unsigned, f);
  u = (u + 0x7FFFu + ((u >> 16) & 1u)) >> 16;
  return (short)u;
}

__device__ inline short8 pack8(const float* src) {
  float4 a = ((const float4*)src)[0];
  float4 b = ((const float4*)src)[1];
  short8 v;
  v[0]=f2bf(a.x); v[1]=f2bf(a.y); v[2]=f2bf(a.z); v[3]=f2bf(a.w);
  v[4]=f2bf(b.x); v[5]=f2bf(b.y); v[6]=f2bf(b.z); v[7]=f2bf(b.w);
  return v;
}

__device__ inline void gload_lds16(const u16* g, char* lds_byte) {
  __builtin_amdgcn_global_load_lds(
      (const __attribute__((address_space(1))) unsigned int*)g,
      (__attribute__((address_space(3))) unsigned int*)lds_byte,
      16, 0, 0);
}

// ---------------- pack kernels ----------------

__global__ __launch_bounds__(256) void pack_x_kernel(
    const float* __restrict__ q, const float* __restrict__ qp, u16* __restrict__ xcat) {
  int o = blockIdx.x * 256 + threadIdx.x;
  int row = o >> 7;
  int kk  = (o & 127) << 3;
  const float* src = (kk < 512) ? (q + (size_t)row * 512 + kk)
                                : (qp + (size_t)row * 512 + (kk - 512));
  short8 v = pack8(src);
  *(short8*)(xcat + (size_t)row * KPROJ + kk) = v;
}

__global__ __launch_bounds__(256) void pack_w_kernel(
    const float* __restrict__ Wqc, const float* __restrict__ Wqp,
    const float* __restrict__ Wkc, const float* __restrict__ Wkp,
    const float* __restrict__ Wv,  const float* __restrict__ Wo,
    const float* __restrict__ bqc, const float* __restrict__ bqp,
    const float* __restrict__ bkc, const float* __restrict__ bkp,
    const float* __restrict__ bv,
    u16* __restrict__ wcat, u16* __restrict__ wo_bf, float* __restrict__ bias_cat) {
  int o = blockIdx.x * 256 + threadIdx.x;
  if (o < 196608) {
    int j = o >> 7;
    int kk = (o & 127) << 3;
    const float* src = nullptr;
    if (j < 512)        src = (kk < 512) ? Wqc + (size_t)j * 512 + kk : Wqp + (size_t)j * 512 + (kk - 512);
    else if (j < 1024) { int jj = j - 512;  src = (kk < 512) ? Wkc + (size_t)jj * 512 + kk : Wkp + (size_t)jj * 512 + (kk - 512); }
    else               { int jj = j - 1024; src = (kk < 512) ? Wv  + (size_t)jj * 512 + kk : nullptr; }
    short8 v = {0,0,0,0,0,0,0,0};
    if (src) v = pack8(src);
    *(short8*)(wcat + (size_t)j * KPROJ + kk) = v;
  } else if (o < 229376) {
    int o2 = o - 196608;
    int j = o2 >> 6;
    int kk = (o2 & 63) << 3;
    short8 v = pack8(Wo + (size_t)j * 512 + kk);
    *(short8*)(wo_bf + (size_t)j * 512 + kk) = v;
  }
  if (o < 1536) {
    float v;
    if (o < 512)       v = bqc[o] + bqp[o];
    else if (o < 1024) v = bkc[o - 512] + bkp[o - 512];
    else               v = bv[o - 1024];
    bias_cat[o] = v;
  }
}

// ---------------- shared 128x128 / BK=64 GEMM mainloop (2 blocks/CU) ----------------
// LDS per buf: A(128x64) at 0, B(128x64) at +16KB; 2 bufs = 64KB total.
// XOR-source swizzle (chunk col ^= row&7) -> conflict-free ds_read_b128.
// One vmcnt(0)+barrier per K-tile; cross-block overlap hides the drain.
// MFMA operands swapped (B as A-operand): lane owns 4 consecutive out-cols.
template <int KDIM>
__device__ inline void gemm128_loop(const u16* __restrict__ A, const u16* __restrict__ Bw,
                                    int m0, int n0, u16* lds, f32x4 (&acc)[4][4]) {
  const int tid = threadIdx.x;
  const int lane = tid & 63, wave = tid >> 6;
  const int wr = wave >> 1, wc = wave & 1;
  const int lr = lane & 15, lg = lane >> 4;

  auto stage = [&](int buf, int t) {
    int k0 = t * 64;
    #pragma unroll
    for (int i = 0; i < 4; ++i) {
      int s = i * 256 + tid;            // chunk 0..1023
      int row = s >> 3, col = s & 7;
      int colp = col ^ (row & 7);       // inverse swizzle on SOURCE, linear dest
      gload_lds16(A + (size_t)(m0 + row) * KDIM + k0 + colp * 8,
                  (char*)lds + (size_t)buf * 32768 + (size_t)(i * 256 + wave * 64) * 16);
      gload_lds16(Bw + (size_t)(n0 + row) * KDIM + k0 + colp * 8,
                  (char*)lds + (size_t)buf * 32768 + 16384 + (size_t)(i * 256 + wave * 64) * 16);
    }
  };

  auto rdA = [&](int buf, int mf, int ks) {
    int rowl = wr * 64 + mf * 16 + lr;
    int ch = (ks * 4 + lg) ^ (rowl & 7);
    return *(const short8*)(lds + (size_t)buf * 16384 + (size_t)rowl * 64 + ch * 8);
  };
  auto rdB = [&](int buf, int nf, int ks) {
    int rowl = wc * 64 + nf * 16 + lr;
    int ch = (ks * 4 + lg) ^ (rowl & 7);
    return *(const short8*)(lds + (size_t)buf * 16384 + 8192 + (size_t)rowl * 64 + ch * 8);
  };

  stage(0, 0);
  asm volatile("s_waitcnt vmcnt(0)" ::: "memory");
  __builtin_amdgcn_s_barrier();

  constexpr int NT = KDIM / 64;
  int cur = 0;
  for (int t = 0; t < NT; ++t) {
    if (t + 1 < NT) stage(cur ^ 1, t + 1);
    short8 bf[4][2], af[4][2];
    #pragma unroll
    for (int nf = 0; nf < 4; ++nf)
      #pragma unroll
      for (int ks = 0; ks < 2; ++ks) bf[nf][ks] = rdB(cur, nf, ks);
    #pragma unroll
    for (int mf = 0; mf < 4; ++mf)
      #pragma unroll
      for (int ks = 0; ks < 2; ++ks) af[mf][ks] = rdA(cur, mf, ks);
    __builtin_amdgcn_s_setprio(1);
    #pragma unroll
    for (int mf = 0; mf < 4; ++mf)
      #pragma unroll
      for (int nf = 0; nf < 4; ++nf)
        #pragma unroll
        for (int ks = 0; ks < 2; ++ks)
          acc[mf][nf] = __builtin_amdgcn_mfma_f32_16x16x32_bf16(
              bf[nf][ks], af[mf][ks], acc[mf][nf], 0, 0, 0);
    __builtin_amdgcn_s_setprio(0);
    asm volatile("s_waitcnt vmcnt(0)" ::: "memory");
    __builtin_amdgcn_s_barrier();
    cur ^= 1;
  }
}

// ---------------- projection GEMM ----------------
__global__ __launch_bounds__(256, 2) void proj_gemm_kernel(
    const u16* __restrict__ Xcat, const u16* __restrict__ Wcat,
    const float* __restrict__ bias_cat,
    u16* __restrict__ Qh, u16* __restrict__ Kh, u16* __restrict__ Vh) {
  __shared__ __align__(16) u16 lds[2 * 16384];   // 64 KB

  // bijective XCD swizzle (1536 blocks, 1536 % 8 == 0)
  int id0 = blockIdx.x;
  int swz = (id0 & 7) * 192 + (id0 >> 3);
  int bx = swz / 12, by = swz % 12;
  const int m0 = bx * 128, n0 = by * 128;

  const int lane = threadIdx.x & 63, wave = threadIdx.x >> 6;
  const int wr = wave >> 1, wc = wave & 1;
  const int lr = lane & 15, lg = lane >> 4;

  f32x4 acc[4][4];
  f32x4 z4 = {0.f, 0.f, 0.f, 0.f};
  #pragma unroll
  for (int mf = 0; mf < 4; ++mf)
    #pragma unroll
    for (int nf = 0; nf < 4; ++nf) acc[mf][nf] = z4;

  gemm128_loop<KPROJ>(Xcat, Wcat, m0, n0, lds, acc);

  // epilogue: lane frag (mf,nf) -> row l = m0+wr*64+mf*16+lr,
  // cols c = n0+wc*64+nf*16+lg*4 .. +3 (consecutive) -> 8B stores
  const int cbase = n0 + wc * 64 + lg * 4;
  #pragma unroll
  for (int mf = 0; mf < 4; ++mf) {
    int lglob = m0 + wr * 64 + mf * 16 + lr;
    int bidx = lglob >> 10, lrow = lglob & 1023;
    #pragma unroll
    for (int nf = 0; nf < 4; ++nf) {
      int c = cbase + nf * 16;
      float4 bb = *(const float4*)&bias_cat[c];
      int sec = c >> 9, cj = c & 511;
      int h = cj >> 6, d0 = cj & 63;
      size_t idx = ((size_t)(bidx * HH + h) * LL + lrow) * DD + d0;
      float v0 = acc[mf][nf][0] + bb.x;
      float v1 = acc[mf][nf][1] + bb.y;
      float v2 = acc[mf][nf][2] + bb.z;
      float v3 = acc[mf][nf][3] + bb.w;
      if (sec == 0) { v0 *= QSCALE; v1 *= QSCALE; v2 *= QSCALE; v3 *= QSCALE; }
      short4v o;
      o[0] = f2bf(v0); o[1] = f2bf(v1); o[2] = f2bf(v2); o[3] = f2bf(v3);
      u16* dst = (sec == 0) ? Qh : (sec == 1) ? Kh : Vh;
      *(short4v*)&dst[idx] = o;
    }
  }
}

// ---------------- output projection + residual ----------------
__global__ __launch_bounds__(256, 2) void out_gemm_kernel(
    const u16* __restrict__ Oh, const u16* __restrict__ Wo_bf,
    const float* __restrict__ bo, const float* __restrict__ query,
    float* __restrict__ out) {
  __shared__ __align__(16) u16 lds[2 * 16384];   // 64 KB

  // bijective XCD swizzle (512 blocks, 512 % 8 == 0)
  int id0 = blockIdx.x;
  int swz = (id0 & 7) * 64 + (id0 >> 3);
  int bx = swz / 4, by = swz % 4;
  const int m0 = bx * 128, n0 = by * 128;

  const int lane = threadIdx.x & 63, wave = threadIdx.x >> 6;
  const int wr = wave >> 1, wc = wave & 1;
  const int lr = lane & 15, lg = lane >> 4;

  f32x4 acc[4][4];
  f32x4 z4 = {0.f, 0.f, 0.f, 0.f};
  #pragma unroll
  for (int mf = 0; mf < 4; ++mf)
    #pragma unroll
    for (int nf = 0; nf < 4; ++nf) acc[mf][nf] = z4;

  gemm128_loop<CC>(Oh, Wo_bf, m0, n0, lds, acc);

  // epilogue: lane owns 4 consecutive cols -> float4 residual-add stores
  const int cbase = n0 + wc * 64 + lg * 4;
  #pragma unroll
  for (int mf = 0; mf < 4; ++mf) {
    int rw = m0 + wr * 64 + mf * 16 + lr;
    #pragma unroll
    for (int nf = 0; nf < 4; ++nf) {
      int c = cbase + nf * 16;
      float4 bb = *(const float4*)&bo[c];
      size_t idx = (size_t)rw * CC + c;
      float4 qq = *(const float4*)&query[idx];
      float4 o;
      o.x = acc[mf][nf][0] + bb.x + qq.x;
      o.y = acc[mf][nf][1] + bb.y + qq.y;
      o.z = acc[mf][nf][2] + bb.z + qq.z;
      o.w = acc[mf][nf][3] + bb.w + qq.w;
      *(float4*)&out[idx] = o;
    }
  }
}

// ---------------- V transpose: Vh[bh][l][d] -> Vt[bh][d][l] ----------------
__global__ __launch_bounds__(256) void vtrans_kernel(
    const u16* __restrict__ Vh, u16* __restrict__ Vt) {
  __shared__ u16 T[64][72];
  int bh = blockIdx.y;
  int l0 = blockIdx.x * 64;
  int t = threadIdx.x;
  const u16* src = Vh + (size_t)bh * LL * DD;
  {
    int l = t >> 2, dq = (t & 3) * 16;
    short8 v0 = *(const short8*)(src + (size_t)(l0 + l) * DD + dq);
    short8 v1 = *(const short8*)(src + (size_t)(l0 + l) * DD + dq + 8);
    #pragma unroll
    for (int j = 0; j < 8; ++j) T[dq + j][l] = (u16)v0[j];
    #pragma unroll
    for (int j = 0; j < 8; ++j) T[dq + 8 + j][l] = (u16)v1[j];
  }
  __syncthreads();
  {
    int d = t >> 2, lq = (t & 3) * 16;
    u16* dst = Vt + (size_t)bh * DD * LL + (size_t)d * LL + l0 + lq;
    *(short8*)dst = *(const short8*)&T[d][lq];
    *(short8*)(dst + 8) = *(const short8*)&T[d][lq + 8];
  }
}

// ---------------- flash attention v3: no-max softmax, 64 q/wave ----------------
__global__ __launch_bounds__(256, 2) void attn_kernel(
    const u16* __restrict__ Qh, const u16* __restrict__ Kh,
    const u16* __restrict__ Vt, u16* __restrict__ Oh) {
  __shared__ __align__(16) u16 Kl[2][64 * 64];
  __shared__ __align__(16) u16 Vl[2][64 * 64];
  __shared__ __align__(16) char Pp[4][8192];   // per-wave 8KB (4 m x 2KB)

  const int tid = threadIdx.x;
  const int lane = tid & 63, wave = tid >> 6;
  const int lr = lane & 15, lg = lane >> 4;
  const int sw = (lr & 7) * 2;
  int n = blockIdx.x;                 // 512 blocks
  int rest = n >> 3;                  // 0..63
  const int bh = (n & 7) * 16 + (rest >> 2);
  const int q0 = (rest & 3) * 256;

  const u16* Qb = Qh + (size_t)bh * LL * DD;
  const u16* Kb = Kh + (size_t)bh * LL * DD;
  const u16* Vb = Vt + (size_t)bh * DD * LL;

  short8 aq[4][2];
  #pragma unroll
  for (int m = 0; m < 4; ++m)
    #pragma unroll
    for (int s = 0; s < 2; ++s)
      aq[m][s] = *(const short8*)(Qb + (size_t)(q0 + wave * 64 + m * 16 + lr) * DD + s * 32 + lg * 8);

  f32x4 z4 = {0.f, 0.f, 0.f, 0.f};
  f32x4 oaccT[4][4];
  #pragma unroll
  for (int m = 0; m < 4; ++m)
    #pragma unroll
    for (int db = 0; db < 4; ++db) oaccT[m][db] = z4;
  float lsums[4] = {0.f, 0.f, 0.f, 0.f};

  auto stage = [&](int buf, int kt) {
    int kk0 = kt * 64;
    #pragma unroll
    for (int i = 0; i < 2; ++i) {
      int c = i * 256 + wave * 64 + lane;
      int row = c >> 3, koct = c & 7;
      int ks = koct ^ (row & 7);
      gload_lds16(Kb + (size_t)(kk0 + row) * DD + ks * 8,
                  (char*)&Kl[buf][0] + (size_t)(i * 4 + wave) * 1024);
      gload_lds16(Vb + (size_t)row * LL + kk0 + ks * 8,
                  (char*)&Vl[buf][0] + (size_t)(i * 4 + wave) * 1024);
    }
  };

  stage(0, 0);
  int cur = 0;
  char* Pw = &Pp[wave][0];
  for (int kt = 0; kt < 16; ++kt) {
    if (kt + 1 < 16) {
      stage(cur ^ 1, kt + 1);
      asm volatile("s_waitcnt vmcnt(4)" ::: "memory");
    } else {
      asm volatile("s_waitcnt vmcnt(0)" ::: "memory");
    }
    __builtin_amdgcn_s_barrier();
    __builtin_amdgcn_sched_barrier(0);

    // ---- S^T = K @ Q^T : K frags shared across all 4 m ----
    short8 ka[2][4];
    #pragma unroll
    for (int s = 0; s < 2; ++s)
      #pragma unroll
      for (int kb = 0; kb < 4; ++kb) {
        int key = kb * 16 + lr;
        int dct = s * 4 + lg;
        ka[s][kb] = *(const short8*)((const char*)&Kl[cur][0] + (size_t)key * 128 + ((dct ^ (key & 7)) << 4));
      }
    f32x4 ps[4][4];
    #pragma unroll
    for (int m = 0; m < 4; ++m)
      #pragma unroll
      for (int kb = 0; kb < 4; ++kb) ps[m][kb] = z4;
    __builtin_amdgcn_s_setprio(1);
    #pragma unroll
    for (int s = 0; s < 2; ++s)
      #pragma unroll
      for (int kb = 0; kb < 4; ++kb)
        #pragma unroll
        for (int m = 0; m < 4; ++m)
          ps[m][kb] = __builtin_amdgcn_mfma_f32_16x16x32_bf16(ka[s][kb], aq[m][s], ps[m][kb], 0, 0, 0);
    __builtin_amdgcn_s_setprio(0);

    // ---- no-max softmax: p = exp2(S); lane-local lsum partials; write P ----
    #pragma unroll
    for (int m = 0; m < 4; ++m) {
      #pragma unroll
      for (int kb = 0; kb < 4; ++kb) {
        float p0, p1, p2, p3;
        asm("v_exp_f32 %0, %1" : "=v"(p0) : "v"(ps[m][kb][0]));
        asm("v_exp_f32 %0, %1" : "=v"(p1) : "v"(ps[m][kb][1]));
        asm("v_exp_f32 %0, %1" : "=v"(p2) : "v"(ps[m][kb][2]));
        asm("v_exp_f32 %0, %1" : "=v"(p3) : "v"(ps[m][kb][3]));
        lsums[m] += (p0 + p1) + (p2 + p3);
        unsigned lo, hi;
        asm("v_cvt_pk_bf16_f32 %0, %1, %2" : "=v"(lo) : "v"(p0), "v"(p1));
        asm("v_cvt_pk_bf16_f32 %0, %1, %2" : "=v"(hi) : "v"(p2), "v"(p3));
        uint2 w; w.x = lo; w.y = hi;
        *(uint2*)(Pw + m * 2048 + lr * 128 + ((((kb * 4 + lg) ^ sw)) << 3)) = w;
      }
    }

    // ---- V fragments (shared across all 4 m) ----
    short8 bv[2][4];
    #pragma unroll
    for (int s = 0; s < 2; ++s)
      #pragma unroll
      for (int db = 0; db < 4; ++db) {
        int d = db * 16 + lr;
        int kct = s * 4 + lg;
        bv[s][db] = *(const short8*)((const char*)&Vl[cur][0] + (size_t)d * 128 + ((kct ^ (d & 7)) << 4));
      }

    asm volatile("s_waitcnt lgkmcnt(0)" ::: "memory");
    __builtin_amdgcn_sched_barrier(0);

    // ---- O^T += V^T @ P for all m ----
    __builtin_amdgcn_s_setprio(1);
    #pragma unroll
    for (int m = 0; m < 4; ++m) {
      #pragma unroll
      for (int s = 0; s < 2; ++s) {
        int val0 = s * 8 + lg * 2;
        uint4 pw = *(const uint4*)(Pw + m * 2048 + lr * 128 + (((val0 ^ sw)) << 3));
        short8 ap = __builtin_bit_cast(short8, pw);
        #pragma unroll
        for (int db = 0; db < 4; ++db)
          oaccT[m][db] = __builtin_amdgcn_mfma_f32_16x16x32_bf16(bv[s][db], ap, oaccT[m][db], 0, 0, 0);
      }
    }
    __builtin_amdgcn_s_setprio(0);

    __builtin_amdgcn_s_barrier();
    cur ^= 1;
  }

  // epilogue: reduce lsum partials across the lg-group once, scale, store
  int b = bh >> 3, h = bh & 7;
  #pragma unroll
  for (int m = 0; m < 4; ++m) {
    float v = lsums[m];
    v += __shfl_xor(v, 16);
    v += __shfl_xor(v, 32);
    float inv = 1.0f / v;
    int q = q0 + wave * 64 + m * 16 + lr;
    #pragma unroll
    for (int db = 0; db < 4; ++db) {
      int d0 = db * 16 + lg * 4;
      short4v o;
      #pragma unroll
      for (int r = 0; r < 4; ++r) o[r] = f2bf(oaccT[m][db][r] * inv);
      *(short4v*)&Oh[(size_t)(b * LL + q) * CC + h * 64 + d0] = o;
    }
  }
}

// ---------------- launcher ----------------
extern "C" void kernel_launch(void* const* d_in, const int* in_sizes, int n_in,
                              void* d_out, int out_size, void* d_ws, size_t ws_size,
                              hipStream_t stream) {
  (void)in_sizes; (void)n_in; (void)out_size;
  const float* query = (const float*)d_in[0];
  const float* qpos  = (const float*)d_in[1];
  const float* Wqc = (const float*)d_in[2];
  const float* bqc = (const float*)d_in[3];
  const float* Wqp = (const float*)d_in[4];
  const float* bqp = (const float*)d_in[5];
  const float* Wkc = (const float*)d_in[6];
  const float* bkc = (const float*)d_in[7];
  const float* Wkp = (const float*)d_in[8];
  const float* bkp = (const float*)d_in[9];
  const float* Wv  = (const float*)d_in[10];
  const float* bv  = (const float*)d_in[11];
  const float* Wo  = (const float*)d_in[12];
  const float* bo  = (const float*)d_in[13];

  char* ws = (char*)d_ws;
  if (ws_size < WS_END) return;

  u16*   Xcat     = (u16*)(ws + WS_XCAT);
  u16*   Wcat     = (u16*)(ws + WS_WCAT);
  u16*   Wo_bf    = (u16*)(ws + WS_WO);
  float* bias_cat = (float*)(ws + WS_BIAS);
  u16*   Qh       = (u16*)(ws + WS_QH);
  u16*   Kh       = (u16*)(ws + WS_KH);
  u16*   Vh       = (u16*)(ws + WS_VH);
  u16*   Oh       = (u16*)(ws + WS_OH);
  u16*   Vtr      = (u16*)(ws + WS_VT);   // aliases Xcat (dead after proj)
  float* out      = (float*)d_out;

  pack_x_kernel<<<dim3(8192), dim3(256), 0, stream>>>(query, qpos, Xcat);
  pack_w_kernel<<<dim3(896), dim3(256), 0, stream>>>(Wqc, Wqp, Wkc, Wkp, Wv, Wo,
                                                     bqc, bqp, bkc, bkp, bv,
                                                     Wcat, Wo_bf, bias_cat);
  proj_gemm_kernel<<<dim3((MROWS / 128) * (NPROJ / 128)), dim3(256), 0, stream>>>(
      Xcat, Wcat, bias_cat, Qh, Kh, Vh);
  vtrans_kernel<<<dim3(LL / 64, BB * HH), dim3(256), 0, stream>>>(Vh, Vtr);
  attn_kernel<<<dim3(512), dim3(256), 0, stream>>>(Qh, Kh, Vtr, Oh);
  out_gemm_kernel<<<dim3((MROWS / 128) * (CC / 128)), dim3(256), 0, stream>>>(
      Oh, Wo_bf, bo, query, out);
}

// Round 11
// 150.681 us; speedup vs baseline: 1.3239x; 1.0578x over previous
//
#include <hip/hip_runtime.h>

typedef __attribute__((ext_vector_type(8))) short short8;
typedef __attribute__((ext_vector_type(4))) short short4v;
typedef __attribute__((ext_vector_type(4))) float f32x4;
typedef unsigned short u16;

#define QSCALE 0.18033688011112042f   /* 0.125 * log2(e): softmax done in exp2 domain */

#define BB 16
#define LL 1024
#define CC 512
#define HH 8
#define DD 64
#define MROWS (BB*LL)      /* 16384 */
#define KPROJ 1024
#define NPROJ 1536

// workspace offsets (bytes). Vt lives in the old Vh slot (proj writes it while
// still reading Xcat, so it must NOT alias Xcat).
#define WS_XCAT   0ull
#define WS_WCAT   (WS_XCAT + (size_t)MROWS*KPROJ*2)
#define WS_WO     (WS_WCAT + (size_t)NPROJ*KPROJ*2)
#define WS_BIAS   (WS_WO   + (size_t)CC*CC*2)
#define WS_QH     (WS_BIAS + 8192)
#define WS_KH     (WS_QH + (size_t)MROWS*CC*2)
#define WS_VT     (WS_KH + (size_t)MROWS*CC*2)
#define WS_OH     (WS_VT + (size_t)MROWS*CC*2)
#define WS_END    (WS_OH + (size_t)MROWS*CC*2)

__device__ inline short f2bf(float f) {
  unsigned u = __builtin_bit_cast(unsigned, f);
  u = (u + 0x7FFFu + ((u >> 16) & 1u)) >> 16;
  return (short)u;
}

__device__ inline short8 pack8(const float* src) {
  float4 a = ((const float4*)src)[0];
  float4 b = ((const float4*)src)[1];
  short8 v;
  v[0]=f2bf(a.x); v[1]=f2bf(a.y); v[2]=f2bf(a.z); v[3]=f2bf(a.w);
  v[4]=f2bf(b.x); v[5]=f2bf(b.y); v[6]=f2bf(b.z); v[7]=f2bf(b.w);
  return v;
}

__device__ inline void gload_lds16(const u16* g, char* lds_byte) {
  __builtin_amdgcn_global_load_lds(
      (const __attribute__((address_space(1))) unsigned int*)g,
      (__attribute__((address_space(3))) unsigned int*)lds_byte,
      16, 0, 0);
}

// ---------------- fused pack kernel (x + w + biases) ----------------
__global__ __launch_bounds__(256) void pack_all_kernel(
    const float* __restrict__ q, const float* __restrict__ qp,
    const float* __restrict__ Wqc, const float* __restrict__ Wqp,
    const float* __restrict__ Wkc, const float* __restrict__ Wkp,
    const float* __restrict__ Wv,  const float* __restrict__ Wo,
    const float* __restrict__ bqc, const float* __restrict__ bqp,
    const float* __restrict__ bkc, const float* __restrict__ bkp,
    const float* __restrict__ bv,
    u16* __restrict__ xcat, u16* __restrict__ wcat, u16* __restrict__ wo_bf,
    float* __restrict__ bias_cat) {
  if (blockIdx.x < 8192) {
    int o = blockIdx.x * 256 + threadIdx.x;
    int row = o >> 7;
    int kk  = (o & 127) << 3;
    const float* src = (kk < 512) ? (q + (size_t)row * 512 + kk)
                                  : (qp + (size_t)row * 512 + (kk - 512));
    short8 v = pack8(src);
    *(short8*)(xcat + (size_t)row * KPROJ + kk) = v;
    return;
  }
  int o = (blockIdx.x - 8192) * 256 + threadIdx.x;
  if (o < 196608) {
    int j = o >> 7;
    int kk = (o & 127) << 3;
    const float* src = nullptr;
    if (j < 512)        src = (kk < 512) ? Wqc + (size_t)j * 512 + kk : Wqp + (size_t)j * 512 + (kk - 512);
    else if (j < 1024) { int jj = j - 512;  src = (kk < 512) ? Wkc + (size_t)jj * 512 + kk : Wkp + (size_t)jj * 512 + (kk - 512); }
    else               { int jj = j - 1024; src = (kk < 512) ? Wv  + (size_t)jj * 512 + kk : nullptr; }
    short8 v = {0,0,0,0,0,0,0,0};
    if (src) v = pack8(src);
    *(short8*)(wcat + (size_t)j * KPROJ + kk) = v;
  } else if (o < 229376) {
    int o2 = o - 196608;
    int j = o2 >> 6;
    int kk = (o2 & 63) << 3;
    short8 v = pack8(Wo + (size_t)j * 512 + kk);
    *(short8*)(wo_bf + (size_t)j * 512 + kk) = v;
  }
  if (o < 1536) {
    float v;
    if (o < 512)       v = bqc[o] + bqp[o];
    else if (o < 1024) v = bkc[o - 512] + bkp[o - 512];
    else               v = bv[o - 1024];
    bias_cat[o] = v;
  }
}

// ---------------- shared 128x128 / BK=64 GEMM mainloop (2 blocks/CU) ----------------
template <int KDIM>
__device__ inline void gemm128_loop(const u16* __restrict__ A, const u16* __restrict__ Bw,
                                    int m0, int n0, u16* lds, f32x4 (&acc)[4][4]) {
  const int tid = threadIdx.x;
  const int lane = tid & 63, wave = tid >> 6;
  const int wr = wave >> 1, wc = wave & 1;
  const int lr = lane & 15, lg = lane >> 4;

  auto stage = [&](int buf, int t) {
    int k0 = t * 64;
    #pragma unroll
    for (int i = 0; i < 4; ++i) {
      int s = i * 256 + tid;            // chunk 0..1023
      int row = s >> 3, col = s & 7;
      int colp = col ^ (row & 7);       // inverse swizzle on SOURCE, linear dest
      gload_lds16(A + (size_t)(m0 + row) * KDIM + k0 + colp * 8,
                  (char*)lds + (size_t)buf * 32768 + (size_t)(i * 256 + wave * 64) * 16);
      gload_lds16(Bw + (size_t)(n0 + row) * KDIM + k0 + colp * 8,
                  (char*)lds + (size_t)buf * 32768 + 16384 + (size_t)(i * 256 + wave * 64) * 16);
    }
  };

  auto rdA = [&](int buf, int mf, int ks) {
    int rowl = wr * 64 + mf * 16 + lr;
    int ch = (ks * 4 + lg) ^ (rowl & 7);
    return *(const short8*)(lds + (size_t)buf * 16384 + (size_t)rowl * 64 + ch * 8);
  };
  auto rdB = [&](int buf, int nf, int ks) {
    int rowl = wc * 64 + nf * 16 + lr;
    int ch = (ks * 4 + lg) ^ (rowl & 7);
    return *(const short8*)(lds + (size_t)buf * 16384 + 8192 + (size_t)rowl * 64 + ch * 8);
  };

  stage(0, 0);
  asm volatile("s_waitcnt vmcnt(0)" ::: "memory");
  __builtin_amdgcn_s_barrier();

  constexpr int NT = KDIM / 64;
  int cur = 0;
  for (int t = 0; t < NT; ++t) {
    if (t + 1 < NT) stage(cur ^ 1, t + 1);
    short8 bf[4][2], af[4][2];
    #pragma unroll
    for (int nf = 0; nf < 4; ++nf)
      #pragma unroll
      for (int ks = 0; ks < 2; ++ks) bf[nf][ks] = rdB(cur, nf, ks);
    #pragma unroll
    for (int mf = 0; mf < 4; ++mf)
      #pragma unroll
      for (int ks = 0; ks < 2; ++ks) af[mf][ks] = rdA(cur, mf, ks);
    __builtin_amdgcn_s_setprio(1);
    #pragma unroll
    for (int mf = 0; mf < 4; ++mf)
      #pragma unroll
      for (int nf = 0; nf < 4; ++nf)
        #pragma unroll
        for (int ks = 0; ks < 2; ++ks)
          acc[mf][nf] = __builtin_amdgcn_mfma_f32_16x16x32_bf16(
              bf[nf][ks], af[mf][ks], acc[mf][nf], 0, 0, 0);
    __builtin_amdgcn_s_setprio(0);
    asm volatile("s_waitcnt vmcnt(0)" ::: "memory");
    __builtin_amdgcn_s_barrier();
    cur ^= 1;
  }
}

// ---------------- projection GEMM (V written pre-transposed via LDS) ----------------
__global__ __launch_bounds__(256, 2) void proj_gemm_kernel(
    const u16* __restrict__ Xcat, const u16* __restrict__ Wcat,
    const float* __restrict__ bias_cat,
    u16* __restrict__ Qh, u16* __restrict__ Kh, u16* __restrict__ Vt) {
  __shared__ __align__(16) u16 lds[2 * 16384];   // 64 KB

  // bijective XCD swizzle (1536 blocks, 1536 % 8 == 0)
  int id0 = blockIdx.x;
  int swz = (id0 & 7) * 192 + (id0 >> 3);
  int bx = swz / 12, by = swz % 12;
  const int m0 = bx * 128, n0 = by * 128;

  const int tid = threadIdx.x;
  const int lane = tid & 63, wave = tid >> 6;
  const int wr = wave >> 1, wc = wave & 1;
  const int lr = lane & 15, lg = lane >> 4;

  f32x4 acc[4][4];
  f32x4 z4 = {0.f, 0.f, 0.f, 0.f};
  #pragma unroll
  for (int mf = 0; mf < 4; ++mf)
    #pragma unroll
    for (int nf = 0; nf < 4; ++nf) acc[mf][nf] = z4;

  gemm128_loop<KPROJ>(Xcat, Wcat, m0, n0, lds, acc);

  if (n0 < 1024) {
    // Q/K epilogue: lane frag (mf,nf) -> row l, 4 consecutive cols -> 8B stores
    const int cbase = n0 + wc * 64 + lg * 4;
    #pragma unroll
    for (int mf = 0; mf < 4; ++mf) {
      int lglob = m0 + wr * 64 + mf * 16 + lr;
      int bidx = lglob >> 10, lrow = lglob & 1023;
      #pragma unroll
      for (int nf = 0; nf < 4; ++nf) {
        int c = cbase + nf * 16;
        float4 bb = *(const float4*)&bias_cat[c];
        int sec = c >> 9, cj = c & 511;
        int h = cj >> 6, d0 = cj & 63;
        size_t idx = ((size_t)(bidx * HH + h) * LL + lrow) * DD + d0;
        float v0 = acc[mf][nf][0] + bb.x;
        float v1 = acc[mf][nf][1] + bb.y;
        float v2 = acc[mf][nf][2] + bb.z;
        float v3 = acc[mf][nf][3] + bb.w;
        if (sec == 0) { v0 *= QSCALE; v1 *= QSCALE; v2 *= QSCALE; v3 *= QSCALE; }
        short4v o;
        o[0] = f2bf(v0); o[1] = f2bf(v1); o[2] = f2bf(v2); o[3] = f2bf(v3);
        u16* dst = (sec == 0) ? Qh : Kh;
        *(short4v*)&dst[idx] = o;
      }
    }
  } else {
    // V epilogue: transpose through the dead 64KB LDS, store Vt[bh][d][l]
    // T[cjl][ll] bf16, row stride 136 u16 (272B, 16B-aligned). 34KB <= 64KB.
    u16* T = lds;
    // mainloop ended with s_barrier: all waves' LDS reads are complete.
    #pragma unroll
    for (int mf = 0; mf < 4; ++mf) {
      int ll = wr * 64 + mf * 16 + lr;
      #pragma unroll
      for (int nf = 0; nf < 4; ++nf) {
        int cjl = wc * 64 + nf * 16 + lg * 4;
        int c = n0 + cjl;
        float4 bb = *(const float4*)&bias_cat[c];
        T[(size_t)(cjl + 0) * 136 + ll] = (u16)f2bf(acc[mf][nf][0] + bb.x);
        T[(size_t)(cjl + 1) * 136 + ll] = (u16)f2bf(acc[mf][nf][1] + bb.y);
        T[(size_t)(cjl + 2) * 136 + ll] = (u16)f2bf(acc[mf][nf][2] + bb.z);
        T[(size_t)(cjl + 3) * 136 + ll] = (u16)f2bf(acc[mf][nf][3] + bb.w);
      }
    }
    __builtin_amdgcn_s_barrier();
    int b = m0 >> 10, lrow0 = m0 & 1023;
    #pragma unroll
    for (int i = 0; i < 8; ++i) {
      int c2 = i * 256 + tid;          // 2048 chunks of 16B
      int r = c2 >> 4;                 // cjl row 0..127
      int o8 = (c2 & 15) * 8;          // l-offset within row
      short8 v = *(const short8*)&T[(size_t)r * 136 + o8];
      int cj = n0 - 1024 + r;
      int h = cj >> 6, d = cj & 63;
      *(short8*)&Vt[((size_t)(b * HH + h) * DD + d) * LL + lrow0 + o8] = v;
    }
  }
}

// ---------------- output projection + residual ----------------
__global__ __launch_bounds__(256, 2) void out_gemm_kernel(
    const u16* __restrict__ Oh, const u16* __restrict__ Wo_bf,
    const float* __restrict__ bo, const float* __restrict__ query,
    float* __restrict__ out) {
  __shared__ __align__(16) u16 lds[2 * 16384];   // 64 KB

  // bijective XCD swizzle (512 blocks, 512 % 8 == 0)
  int id0 = blockIdx.x;
  int swz = (id0 & 7) * 64 + (id0 >> 3);
  int bx = swz / 4, by = swz % 4;
  const int m0 = bx * 128, n0 = by * 128;

  const int lane = threadIdx.x & 63, wave = threadIdx.x >> 6;
  const int wr = wave >> 1, wc = wave & 1;
  const int lr = lane & 15, lg = lane >> 4;

  f32x4 acc[4][4];
  f32x4 z4 = {0.f, 0.f, 0.f, 0.f};
  #pragma unroll
  for (int mf = 0; mf < 4; ++mf)
    #pragma unroll
    for (int nf = 0; nf < 4; ++nf) acc[mf][nf] = z4;

  gemm128_loop<CC>(Oh, Wo_bf, m0, n0, lds, acc);

  // epilogue: lane owns 4 consecutive cols -> float4 residual-add stores
  const int cbase = n0 + wc * 64 + lg * 4;
  #pragma unroll
  for (int mf = 0; mf < 4; ++mf) {
    int rw = m0 + wr * 64 + mf * 16 + lr;
    #pragma unroll
    for (int nf = 0; nf < 4; ++nf) {
      int c = cbase + nf * 16;
      float4 bb = *(const float4*)&bo[c];
      size_t idx = (size_t)rw * CC + c;
      float4 qq = *(const float4*)&query[idx];
      float4 o;
      o.x = acc[mf][nf][0] + bb.x + qq.x;
      o.y = acc[mf][nf][1] + bb.y + qq.y;
      o.z = acc[mf][nf][2] + bb.z + qq.z;
      o.w = acc[mf][nf][3] + bb.w + qq.w;
      *(float4*)&out[idx] = o;
    }
  }
}

// ---------------- flash attention v3: no-max softmax, 64 q/wave ----------------
__global__ __launch_bounds__(256, 2) void attn_kernel(
    const u16* __restrict__ Qh, const u16* __restrict__ Kh,
    const u16* __restrict__ Vt, u16* __restrict__ Oh) {
  __shared__ __align__(16) u16 Kl[2][64 * 64];
  __shared__ __align__(16) u16 Vl[2][64 * 64];
  __shared__ __align__(16) char Pp[4][8192];   // per-wave 8KB (4 m x 2KB)

  const int tid = threadIdx.x;
  const int lane = tid & 63, wave = tid >> 6;
  const int lr = lane & 15, lg = lane >> 4;
  const int sw = (lr & 7) * 2;
  int n = blockIdx.x;                 // 512 blocks
  int rest = n >> 3;                  // 0..63
  const int bh = (n & 7) * 16 + (rest >> 2);
  const int q0 = (rest & 3) * 256;

  const u16* Qb = Qh + (size_t)bh * LL * DD;
  const u16* Kb = Kh + (size_t)bh * LL * DD;
  const u16* Vb = Vt + (size_t)bh * DD * LL;

  short8 aq[4][2];
  #pragma unroll
  for (int m = 0; m < 4; ++m)
    #pragma unroll
    for (int s = 0; s < 2; ++s)
      aq[m][s] = *(const short8*)(Qb + (size_t)(q0 + wave * 64 + m * 16 + lr) * DD + s * 32 + lg * 8);

  f32x4 z4 = {0.f, 0.f, 0.f, 0.f};
  f32x4 oaccT[4][4];
  #pragma unroll
  for (int m = 0; m < 4; ++m)
    #pragma unroll
    for (int db = 0; db < 4; ++db) oaccT[m][db] = z4;
  float lsums[4] = {0.f, 0.f, 0.f, 0.f};

  auto stage = [&](int buf, int kt) {
    int kk0 = kt * 64;
    #pragma unroll
    for (int i = 0; i < 2; ++i) {
      int c = i * 256 + wave * 64 + lane;
      int row = c >> 3, koct = c & 7;
      int ks = koct ^ (row & 7);
      gload_lds16(Kb + (size_t)(kk0 + row) * DD + ks * 8,
                  (char*)&Kl[buf][0] + (size_t)(i * 4 + wave) * 1024);
      gload_lds16(Vb + (size_t)row * LL + kk0 + ks * 8,
                  (char*)&Vl[buf][0] + (size_t)(i * 4 + wave) * 1024);
    }
  };

  stage(0, 0);
  int cur = 0;
  char* Pw = &Pp[wave][0];
  for (int kt = 0; kt < 16; ++kt) {
    if (kt + 1 < 16) {
      stage(cur ^ 1, kt + 1);
      asm volatile("s_waitcnt vmcnt(4)" ::: "memory");
    } else {
      asm volatile("s_waitcnt vmcnt(0)" ::: "memory");
    }
    __builtin_amdgcn_s_barrier();
    __builtin_amdgcn_sched_barrier(0);

    // ---- S^T = K @ Q^T : K frags shared across all 4 m ----
    short8 ka[2][4];
    #pragma unroll
    for (int s = 0; s < 2; ++s)
      #pragma unroll
      for (int kb = 0; kb < 4; ++kb) {
        int key = kb * 16 + lr;
        int dct = s * 4 + lg;
        ka[s][kb] = *(const short8*)((const char*)&Kl[cur][0] + (size_t)key * 128 + ((dct ^ (key & 7)) << 4));
      }
    f32x4 ps[4][4];
    #pragma unroll
    for (int m = 0; m < 4; ++m)
      #pragma unroll
      for (int kb = 0; kb < 4; ++kb) ps[m][kb] = z4;
    __builtin_amdgcn_s_setprio(1);
    #pragma unroll
    for (int s = 0; s < 2; ++s)
      #pragma unroll
      for (int kb = 0; kb < 4; ++kb)
        #pragma unroll
        for (int m = 0; m < 4; ++m)
          ps[m][kb] = __builtin_amdgcn_mfma_f32_16x16x32_bf16(ka[s][kb], aq[m][s], ps[m][kb], 0, 0, 0);
    __builtin_amdgcn_s_setprio(0);

    // ---- no-max softmax: p = exp2(S); lane-local lsum partials; write P ----
    #pragma unroll
    for (int m = 0; m < 4; ++m) {
      #pragma unroll
      for (int kb = 0; kb < 4; ++kb) {
        float p0, p1, p2, p3;
        asm("v_exp_f32 %0, %1" : "=v"(p0) : "v"(ps[m][kb][0]));
        asm("v_exp_f32 %0, %1" : "=v"(p1) : "v"(ps[m][kb][1]));
        asm("v_exp_f32 %0, %1" : "=v"(p2) : "v"(ps[m][kb][2]));
        asm("v_exp_f32 %0, %1" : "=v"(p3) : "v"(ps[m][kb][3]));
        lsums[m] += (p0 + p1) + (p2 + p3);
        unsigned lo, hi;
        asm("v_cvt_pk_bf16_f32 %0, %1, %2" : "=v"(lo) : "v"(p0), "v"(p1));
        asm("v_cvt_pk_bf16_f32 %0, %1, %2" : "=v"(hi) : "v"(p2), "v"(p3));
        uint2 w; w.x = lo; w.y = hi;
        *(uint2*)(Pw + m * 2048 + lr * 128 + ((((kb * 4 + lg) ^ sw)) << 3)) = w;
      }
    }

    // ---- V fragments (shared across all 4 m) ----
    short8 bv[2][4];
    #pragma unroll
    for (int s = 0; s < 2; ++s)
      #pragma unroll
      for (int db = 0; db < 4; ++db) {
        int d = db * 16 + lr;
        int kct = s * 4 + lg;
        bv[s][db] = *(const short8*)((const char*)&Vl[cur][0] + (size_t)d * 128 + ((kct ^ (d & 7)) << 4));
      }

    asm volatile("s_waitcnt lgkmcnt(0)" ::: "memory");
    __builtin_amdgcn_sched_barrier(0);

    // ---- O^T += V^T @ P for all m ----
    __builtin_amdgcn_s_setprio(1);
    #pragma unroll
    for (int m = 0; m < 4; ++m) {
      #pragma unroll
      for (int s = 0; s < 2; ++s) {
        int val0 = s * 8 + lg * 2;
        uint4 pw = *(const uint4*)(Pw + m * 2048 + lr * 128 + (((val0 ^ sw)) << 3));
        short8 ap = __builtin_bit_cast(short8, pw);
        #pragma unroll
        for (int db = 0; db < 4; ++db)
          oaccT[m][db] = __builtin_amdgcn_mfma_f32_16x16x32_bf16(bv[s][db], ap, oaccT[m][db], 0, 0, 0);
      }
    }
    __builtin_amdgcn_s_setprio(0);

    __builtin_amdgcn_s_barrier();
    cur ^= 1;
  }

  // epilogue: reduce lsum partials across the lg-group once, scale, store
  int b = bh >> 3, h = bh & 7;
  #pragma unroll
  for (int m = 0; m < 4; ++m) {
    float v = lsums[m];
    v += __shfl_xor(v, 16);
    v += __shfl_xor(v, 32);
    float inv = 1.0f / v;
    int q = q0 + wave * 64 + m * 16 + lr;
    #pragma unroll
    for (int db = 0; db < 4; ++db) {
      int d0 = db * 16 + lg * 4;
      short4v o;
      #pragma unroll
      for (int r = 0; r < 4; ++r) o[r] = f2bf(oaccT[m][db][r] * inv);
      *(short4v*)&Oh[(size_t)(b * LL + q) * CC + h * 64 + d0] = o;
    }
  }
}

// ---------------- launcher ----------------
extern "C" void kernel_launch(void* const* d_in, const int* in_sizes, int n_in,
                              void* d_out, int out_size, void* d_ws, size_t ws_size,
                              hipStream_t stream) {
  (void)in_sizes; (void)n_in; (void)out_size;
  const float* query = (const float*)d_in[0];
  const float* qpos  = (const float*)d_in[1];
  const float* Wqc = (const float*)d_in[2];
  const float* bqc = (const float*)d_in[3];
  const float* Wqp = (const float*)d_in[4];
  const float* bqp = (const float*)d_in[5];
  const float* Wkc = (const float*)d_in[6];
  const float* bkc = (const float*)d_in[7];
  const float* Wkp = (const float*)d_in[8];
  const float* bkp = (const float*)d_in[9];
  const float* Wv  = (const float*)d_in[10];
  const float* bv  = (const float*)d_in[11];
  const float* Wo  = (const float*)d_in[12];
  const float* bo  = (const float*)d_in[13];

  char* ws = (char*)d_ws;
  if (ws_size < WS_END) return;

  u16*   Xcat     = (u16*)(ws + WS_XCAT);
  u16*   Wcat     = (u16*)(ws + WS_WCAT);
  u16*   Wo_bf    = (u16*)(ws + WS_WO);
  float* bias_cat = (float*)(ws + WS_BIAS);
  u16*   Qh       = (u16*)(ws + WS_QH);
  u16*   Kh       = (u16*)(ws + WS_KH);
  u16*   Vtr      = (u16*)(ws + WS_VT);
  u16*   Oh       = (u16*)(ws + WS_OH);
  float* out      = (float*)d_out;

  pack_all_kernel<<<dim3(9088), dim3(256), 0, stream>>>(
      query, qpos, Wqc, Wqp, Wkc, Wkp, Wv, Wo,
      bqc, bqp, bkc, bkp, bv, Xcat, Wcat, Wo_bf, bias_cat);
  proj_gemm_kernel<<<dim3((MROWS / 128) * (NPROJ / 128)), dim3(256), 0, stream>>>(
      Xcat, Wcat, bias_cat, Qh, Kh, Vtr);
  attn_kernel<<<dim3(512), dim3(256), 0, stream>>>(Qh, Kh, Vtr, Oh);
  out_gemm_kernel<<<dim3((MROWS / 128) * (CC / 128)), dim3(256), 0, stream>>>(
      Oh, Wo_bf, bo, query, out);
}

// Round 12
// 145.178 us; speedup vs baseline: 1.3741x; 1.0379x over previous
//
#include <hip/hip_runtime.h>

typedef __attribute__((ext_vector_type(8))) short short8;
typedef __attribute__((ext_vector_type(4))) short short4v;
typedef __attribute__((ext_vector_type(4))) float f32x4;
typedef unsigned short u16;

#define QSCALE 0.18033688011112042f   /* 0.125 * log2(e): softmax done in exp2 domain */

#define BB 16
#define LL 1024
#define CC 512
#define HH 8
#define DD 64
#define MROWS (BB*LL)      /* 16384 */
#define KPROJ 1024
#define NPROJ 1536

// workspace offsets (bytes). Vt lives in the old Vh slot (proj writes it while
// still reading Xcat, so it must NOT alias Xcat).
#define WS_XCAT   0ull
#define WS_WCAT   (WS_XCAT + (size_t)MROWS*KPROJ*2)
#define WS_WO     (WS_WCAT + (size_t)NPROJ*KPROJ*2)
#define WS_BIAS   (WS_WO   + (size_t)CC*CC*2)
#define WS_QH     (WS_BIAS + 8192)
#define WS_KH     (WS_QH + (size_t)MROWS*CC*2)
#define WS_VT     (WS_KH + (size_t)MROWS*CC*2)
#define WS_OH     (WS_VT + (size_t)MROWS*CC*2)
#define WS_END    (WS_OH + (size_t)MROWS*CC*2)

__device__ inline short f2bf(float f) {
  unsigned u = __builtin_bit_cast(unsigned, f);
  u = (u + 0x7FFFu + ((u >> 16) & 1u)) >> 16;
  return (short)u;
}

__device__ inline short8 pack8(const float* src) {
  float4 a = ((const float4*)src)[0];
  float4 b = ((const float4*)src)[1];
  short8 v;
  v[0]=f2bf(a.x); v[1]=f2bf(a.y); v[2]=f2bf(a.z); v[3]=f2bf(a.w);
  v[4]=f2bf(b.x); v[5]=f2bf(b.y); v[6]=f2bf(b.z); v[7]=f2bf(b.w);
  return v;
}

__device__ inline void gload_lds16(const u16* g, char* lds_byte) {
  __builtin_amdgcn_global_load_lds(
      (const __attribute__((address_space(1))) unsigned int*)g,
      (__attribute__((address_space(3))) unsigned int*)lds_byte,
      16, 0, 0);
}

// ---------------- fused pack kernel (x + w + biases) ----------------
__global__ __launch_bounds__(256) void pack_all_kernel(
    const float* __restrict__ q, const float* __restrict__ qp,
    const float* __restrict__ Wqc, const float* __restrict__ Wqp,
    const float* __restrict__ Wkc, const float* __restrict__ Wkp,
    const float* __restrict__ Wv,  const float* __restrict__ Wo,
    const float* __restrict__ bqc, const float* __restrict__ bqp,
    const float* __restrict__ bkc, const float* __restrict__ bkp,
    const float* __restrict__ bv,
    u16* __restrict__ xcat, u16* __restrict__ wcat, u16* __restrict__ wo_bf,
    float* __restrict__ bias_cat) {
  if (blockIdx.x < 8192) {
    int o = blockIdx.x * 256 + threadIdx.x;
    int row = o >> 7;
    int kk  = (o & 127) << 3;
    const float* src = (kk < 512) ? (q + (size_t)row * 512 + kk)
                                  : (qp + (size_t)row * 512 + (kk - 512));
    short8 v = pack8(src);
    *(short8*)(xcat + (size_t)row * KPROJ + kk) = v;
    return;
  }
  int o = (blockIdx.x - 8192) * 256 + threadIdx.x;
  if (o < 196608) {
    int j = o >> 7;
    int kk = (o & 127) << 3;
    const float* src = nullptr;
    if (j < 512)        src = (kk < 512) ? Wqc + (size_t)j * 512 + kk : Wqp + (size_t)j * 512 + (kk - 512);
    else if (j < 1024) { int jj = j - 512;  src = (kk < 512) ? Wkc + (size_t)jj * 512 + kk : Wkp + (size_t)jj * 512 + (kk - 512); }
    else               { int jj = j - 1024; src = (kk < 512) ? Wv  + (size_t)jj * 512 + kk : nullptr; }
    short8 v = {0,0,0,0,0,0,0,0};
    if (src) v = pack8(src);
    *(short8*)(wcat + (size_t)j * KPROJ + kk) = v;
  } else if (o < 229376) {
    int o2 = o - 196608;
    int j = o2 >> 6;
    int kk = (o2 & 63) << 3;
    short8 v = pack8(Wo + (size_t)j * 512 + kk);
    *(short8*)(wo_bf + (size_t)j * 512 + kk) = v;
  }
  if (o < 1536) {
    float v;
    if (o < 512)       v = bqc[o] + bqp[o];
    else if (o < 1024) v = bkc[o - 512] + bkp[o - 512];
    else               v = bv[o - 1024];
    bias_cat[o] = v;
  }
}

// ---------------- shared 128x128 / BK=64 GEMM mainloop (2 blocks/CU) ----------------
// nt = number of 64-wide K-tiles actually computed (KDIM is the row stride).
template <int KDIM>
__device__ inline void gemm128_loop(const u16* __restrict__ A, const u16* __restrict__ Bw,
                                    int m0, int n0, int nt, u16* lds, f32x4 (&acc)[4][4]) {
  const int tid = threadIdx.x;
  const int lane = tid & 63, wave = tid >> 6;
  const int wr = wave >> 1, wc = wave & 1;
  const int lr = lane & 15, lg = lane >> 4;

  auto stage = [&](int buf, int t) {
    int k0 = t * 64;
    #pragma unroll
    for (int i = 0; i < 4; ++i) {
      int s = i * 256 + tid;            // chunk 0..1023
      int row = s >> 3, col = s & 7;
      int colp = col ^ (row & 7);       // inverse swizzle on SOURCE, linear dest
      gload_lds16(A + (size_t)(m0 + row) * KDIM + k0 + colp * 8,
                  (char*)lds + (size_t)buf * 32768 + (size_t)(i * 256 + wave * 64) * 16);
      gload_lds16(Bw + (size_t)(n0 + row) * KDIM + k0 + colp * 8,
                  (char*)lds + (size_t)buf * 32768 + 16384 + (size_t)(i * 256 + wave * 64) * 16);
    }
  };

  auto rdA = [&](int buf, int mf, int ks) {
    int rowl = wr * 64 + mf * 16 + lr;
    int ch = (ks * 4 + lg) ^ (rowl & 7);
    return *(const short8*)(lds + (size_t)buf * 16384 + (size_t)rowl * 64 + ch * 8);
  };
  auto rdB = [&](int buf, int nf, int ks) {
    int rowl = wc * 64 + nf * 16 + lr;
    int ch = (ks * 4 + lg) ^ (rowl & 7);
    return *(const short8*)(lds + (size_t)buf * 16384 + 8192 + (size_t)rowl * 64 + ch * 8);
  };

  stage(0, 0);
  asm volatile("s_waitcnt vmcnt(0)" ::: "memory");
  __builtin_amdgcn_s_barrier();

  int cur = 0;
  for (int t = 0; t < nt; ++t) {
    if (t + 1 < nt) stage(cur ^ 1, t + 1);
    short8 bf[4][2], af[4][2];
    #pragma unroll
    for (int nf = 0; nf < 4; ++nf)
      #pragma unroll
      for (int ks = 0; ks < 2; ++ks) bf[nf][ks] = rdB(cur, nf, ks);
    #pragma unroll
    for (int mf = 0; mf < 4; ++mf)
      #pragma unroll
      for (int ks = 0; ks < 2; ++ks) af[mf][ks] = rdA(cur, mf, ks);
    __builtin_amdgcn_s_setprio(1);
    #pragma unroll
    for (int mf = 0; mf < 4; ++mf)
      #pragma unroll
      for (int nf = 0; nf < 4; ++nf)
        #pragma unroll
        for (int ks = 0; ks < 2; ++ks)
          acc[mf][nf] = __builtin_amdgcn_mfma_f32_16x16x32_bf16(
              bf[nf][ks], af[mf][ks], acc[mf][nf], 0, 0, 0);
    __builtin_amdgcn_s_setprio(0);
    asm volatile("s_waitcnt vmcnt(0)" ::: "memory");
    __builtin_amdgcn_s_barrier();
    cur ^= 1;
  }
}

// ---------------- projection GEMM (V written pre-transposed via LDS) ----------------
// V-column blocks (n0 >= 1024) run only nt=8 K-tiles: Wcat's V rows are ZERO for
// k >= 512 (V has no pos term), so K = 0..511 is the exact support.
__global__ __launch_bounds__(256, 2) void proj_gemm_kernel(
    const u16* __restrict__ Xcat, const u16* __restrict__ Wcat,
    const float* __restrict__ bias_cat,
    u16* __restrict__ Qh, u16* __restrict__ Kh, u16* __restrict__ Vt) {
  __shared__ __align__(16) u16 lds[2 * 16384];   // 64 KB

  // bijective XCD swizzle (1536 blocks, 1536 % 8 == 0)
  int id0 = blockIdx.x;
  int swz = (id0 & 7) * 192 + (id0 >> 3);
  int bx = swz / 12, by = swz % 12;
  const int m0 = bx * 128, n0 = by * 128;

  const int tid = threadIdx.x;
  const int lane = tid & 63, wave = tid >> 6;
  const int wr = wave >> 1, wc = wave & 1;
  const int lr = lane & 15, lg = lane >> 4;

  f32x4 acc[4][4];
  f32x4 z4 = {0.f, 0.f, 0.f, 0.f};
  #pragma unroll
  for (int mf = 0; mf < 4; ++mf)
    #pragma unroll
    for (int nf = 0; nf < 4; ++nf) acc[mf][nf] = z4;

  const int nt = (n0 >= 1024) ? 8 : 16;
  gemm128_loop<KPROJ>(Xcat, Wcat, m0, n0, nt, lds, acc);

  if (n0 < 1024) {
    // Q/K epilogue: lane frag (mf,nf) -> row l, 4 consecutive cols -> 8B stores
    const int cbase = n0 + wc * 64 + lg * 4;
    #pragma unroll
    for (int mf = 0; mf < 4; ++mf) {
      int lglob = m0 + wr * 64 + mf * 16 + lr;
      int bidx = lglob >> 10, lrow = lglob & 1023;
      #pragma unroll
      for (int nf = 0; nf < 4; ++nf) {
        int c = cbase + nf * 16;
        float4 bb = *(const float4*)&bias_cat[c];
        int sec = c >> 9, cj = c & 511;
        int h = cj >> 6, d0 = cj & 63;
        size_t idx = ((size_t)(bidx * HH + h) * LL + lrow) * DD + d0;
        float v0 = acc[mf][nf][0] + bb.x;
        float v1 = acc[mf][nf][1] + bb.y;
        float v2 = acc[mf][nf][2] + bb.z;
        float v3 = acc[mf][nf][3] + bb.w;
        if (sec == 0) { v0 *= QSCALE; v1 *= QSCALE; v2 *= QSCALE; v3 *= QSCALE; }
        short4v o;
        o[0] = f2bf(v0); o[1] = f2bf(v1); o[2] = f2bf(v2); o[3] = f2bf(v3);
        u16* dst = (sec == 0) ? Qh : Kh;
        *(short4v*)&dst[idx] = o;
      }
    }
  } else {
    // V epilogue: transpose through the dead 64KB LDS, store Vt[bh][d][l]
    // T[cjl][ll] bf16, row stride 136 u16 (272B, 16B-aligned). 34KB <= 64KB.
    u16* T = lds;
    // mainloop ended with s_barrier: all waves' LDS reads are complete.
    #pragma unroll
    for (int mf = 0; mf < 4; ++mf) {
      int ll = wr * 64 + mf * 16 + lr;
      #pragma unroll
      for (int nf = 0; nf < 4; ++nf) {
        int cjl = wc * 64 + nf * 16 + lg * 4;
        int c = n0 + cjl;
        float4 bb = *(const float4*)&bias_cat[c];
        T[(size_t)(cjl + 0) * 136 + ll] = (u16)f2bf(acc[mf][nf][0] + bb.x);
        T[(size_t)(cjl + 1) * 136 + ll] = (u16)f2bf(acc[mf][nf][1] + bb.y);
        T[(size_t)(cjl + 2) * 136 + ll] = (u16)f2bf(acc[mf][nf][2] + bb.z);
        T[(size_t)(cjl + 3) * 136 + ll] = (u16)f2bf(acc[mf][nf][3] + bb.w);
      }
    }
    __builtin_amdgcn_s_barrier();
    int b = m0 >> 10, lrow0 = m0 & 1023;
    #pragma unroll
    for (int i = 0; i < 8; ++i) {
      int c2 = i * 256 + tid;          // 2048 chunks of 16B
      int r = c2 >> 4;                 // cjl row 0..127
      int o8 = (c2 & 15) * 8;          // l-offset within row
      short8 v = *(const short8*)&T[(size_t)r * 136 + o8];
      int cj = n0 - 1024 + r;
      int h = cj >> 6, d = cj & 63;
      *(short8*)&Vt[((size_t)(b * HH + h) * DD + d) * LL + lrow0 + o8] = v;
    }
  }
}

// ---------------- output projection + residual ----------------
__global__ __launch_bounds__(256, 2) void out_gemm_kernel(
    const u16* __restrict__ Oh, const u16* __restrict__ Wo_bf,
    const float* __restrict__ bo, const float* __restrict__ query,
    float* __restrict__ out) {
  __shared__ __align__(16) u16 lds[2 * 16384];   // 64 KB

  // bijective XCD swizzle (512 blocks, 512 % 8 == 0)
  int id0 = blockIdx.x;
  int swz = (id0 & 7) * 64 + (id0 >> 3);
  int bx = swz / 4, by = swz % 4;
  const int m0 = bx * 128, n0 = by * 128;

  const int lane = threadIdx.x & 63, wave = threadIdx.x >> 6;
  const int wr = wave >> 1, wc = wave & 1;
  const int lr = lane & 15, lg = lane >> 4;

  f32x4 acc[4][4];
  f32x4 z4 = {0.f, 0.f, 0.f, 0.f};
  #pragma unroll
  for (int mf = 0; mf < 4; ++mf)
    #pragma unroll
    for (int nf = 0; nf < 4; ++nf) acc[mf][nf] = z4;

  gemm128_loop<CC>(Oh, Wo_bf, m0, n0, CC / 64, lds, acc);

  // epilogue: lane owns 4 consecutive cols -> float4 residual-add stores
  const int cbase = n0 + wc * 64 + lg * 4;
  #pragma unroll
  for (int mf = 0; mf < 4; ++mf) {
    int rw = m0 + wr * 64 + mf * 16 + lr;
    #pragma unroll
    for (int nf = 0; nf < 4; ++nf) {
      int c = cbase + nf * 16;
      float4 bb = *(const float4*)&bo[c];
      size_t idx = (size_t)rw * CC + c;
      float4 qq = *(const float4*)&query[idx];
      float4 o;
      o.x = acc[mf][nf][0] + bb.x + qq.x;
      o.y = acc[mf][nf][1] + bb.y + qq.y;
      o.z = acc[mf][nf][2] + bb.z + qq.z;
      o.w = acc[mf][nf][3] + bb.w + qq.w;
      *(float4*)&out[idx] = o;
    }
  }
}

// ---------------- flash attention v3: no-max softmax, 64 q/wave ----------------
__global__ __launch_bounds__(256, 2) void attn_kernel(
    const u16* __restrict__ Qh, const u16* __restrict__ Kh,
    const u16* __restrict__ Vt, u16* __restrict__ Oh) {
  __shared__ __align__(16) u16 Kl[2][64 * 64];
  __shared__ __align__(16) u16 Vl[2][64 * 64];
  __shared__ __align__(16) char Pp[4][8192];   // per-wave 8KB (4 m x 2KB)

  const int tid = threadIdx.x;
  const int lane = tid & 63, wave = tid >> 6;
  const int lr = lane & 15, lg = lane >> 4;
  const int sw = (lr & 7) * 2;
  int n = blockIdx.x;                 // 512 blocks
  int rest = n >> 3;                  // 0..63
  const int bh = (n & 7) * 16 + (rest >> 2);
  const int q0 = (rest & 3) * 256;

  const u16* Qb = Qh + (size_t)bh * LL * DD;
  const u16* Kb = Kh + (size_t)bh * LL * DD;
  const u16* Vb = Vt + (size_t)bh * DD * LL;

  short8 aq[4][2];
  #pragma unroll
  for (int m = 0; m < 4; ++m)
    #pragma unroll
    for (int s = 0; s < 2; ++s)
      aq[m][s] = *(const short8*)(Qb + (size_t)(q0 + wave * 64 + m * 16 + lr) * DD + s * 32 + lg * 8);

  f32x4 z4 = {0.f, 0.f, 0.f, 0.f};
  f32x4 oaccT[4][4];
  #pragma unroll
  for (int m = 0; m < 4; ++m)
    #pragma unroll
    for (int db = 0; db < 4; ++db) oaccT[m][db] = z4;
  float lsums[4] = {0.f, 0.f, 0.f, 0.f};

  auto stage = [&](int buf, int kt) {
    int kk0 = kt * 64;
    #pragma unroll
    for (int i = 0; i < 2; ++i) {
      int c = i * 256 + wave * 64 + lane;
      int row = c >> 3, koct = c & 7;
      int ks = koct ^ (row & 7);
      gload_lds16(Kb + (size_t)(kk0 + row) * DD + ks * 8,
                  (char*)&Kl[buf][0] + (size_t)(i * 4 + wave) * 1024);
      gload_lds16(Vb + (size_t)row * LL + kk0 + ks * 8,
                  (char*)&Vl[buf][0] + (size_t)(i * 4 + wave) * 1024);
    }
  };

  stage(0, 0);
  int cur = 0;
  char* Pw = &Pp[wave][0];
  for (int kt = 0; kt < 16; ++kt) {
    if (kt + 1 < 16) {
      stage(cur ^ 1, kt + 1);
      asm volatile("s_waitcnt vmcnt(4)" ::: "memory");
    } else {
      asm volatile("s_waitcnt vmcnt(0)" ::: "memory");
    }
    __builtin_amdgcn_s_barrier();
    __builtin_amdgcn_sched_barrier(0);

    // ---- S^T = K @ Q^T : K frags shared across all 4 m ----
    short8 ka[2][4];
    #pragma unroll
    for (int s = 0; s < 2; ++s)
      #pragma unroll
      for (int kb = 0; kb < 4; ++kb) {
        int key = kb * 16 + lr;
        int dct = s * 4 + lg;
        ka[s][kb] = *(const short8*)((const char*)&Kl[cur][0] + (size_t)key * 128 + ((dct ^ (key & 7)) << 4));
      }
    f32x4 ps[4][4];
    #pragma unroll
    for (int m = 0; m < 4; ++m)
      #pragma unroll
      for (int kb = 0; kb < 4; ++kb) ps[m][kb] = z4;
    __builtin_amdgcn_s_setprio(1);
    #pragma unroll
    for (int s = 0; s < 2; ++s)
      #pragma unroll
      for (int kb = 0; kb < 4; ++kb)
        #pragma unroll
        for (int m = 0; m < 4; ++m)
          ps[m][kb] = __builtin_amdgcn_mfma_f32_16x16x32_bf16(ka[s][kb], aq[m][s], ps[m][kb], 0, 0, 0);
    __builtin_amdgcn_s_setprio(0);

    // ---- no-max softmax: p = exp2(S); lane-local lsum partials; write P ----
    #pragma unroll
    for (int m = 0; m < 4; ++m) {
      #pragma unroll
      for (int kb = 0; kb < 4; ++kb) {
        float p0, p1, p2, p3;
        asm("v_exp_f32 %0, %1" : "=v"(p0) : "v"(ps[m][kb][0]));
        asm("v_exp_f32 %0, %1" : "=v"(p1) : "v"(ps[m][kb][1]));
        asm("v_exp_f32 %0, %1" : "=v"(p2) : "v"(ps[m][kb][2]));
        asm("v_exp_f32 %0, %1" : "=v"(p3) : "v"(ps[m][kb][3]));
        lsums[m] += (p0 + p1) + (p2 + p3);
        unsigned lo, hi;
        asm("v_cvt_pk_bf16_f32 %0, %1, %2" : "=v"(lo) : "v"(p0), "v"(p1));
        asm("v_cvt_pk_bf16_f32 %0, %1, %2" : "=v"(hi) : "v"(p2), "v"(p3));
        uint2 w; w.x = lo; w.y = hi;
        *(uint2*)(Pw + m * 2048 + lr * 128 + ((((kb * 4 + lg) ^ sw)) << 3)) = w;
      }
    }

    // ---- V fragments (shared across all 4 m) ----
    short8 bv[2][4];
    #pragma unroll
    for (int s = 0; s < 2; ++s)
      #pragma unroll
      for (int db = 0; db < 4; ++db) {
        int d = db * 16 + lr;
        int kct = s * 4 + lg;
        bv[s][db] = *(const short8*)((const char*)&Vl[cur][0] + (size_t)d * 128 + ((kct ^ (d & 7)) << 4));
      }

    asm volatile("s_waitcnt lgkmcnt(0)" ::: "memory");
    __builtin_amdgcn_sched_barrier(0);

    // ---- O^T += V^T @ P for all m ----
    __builtin_amdgcn_s_setprio(1);
    #pragma unroll
    for (int m = 0; m < 4; ++m) {
      #pragma unroll
      for (int s = 0; s < 2; ++s) {
        int val0 = s * 8 + lg * 2;
        uint4 pw = *(const uint4*)(Pw + m * 2048 + lr * 128 + (((val0 ^ sw)) << 3));
        short8 ap = __builtin_bit_cast(short8, pw);
        #pragma unroll
        for (int db = 0; db < 4; ++db)
          oaccT[m][db] = __builtin_amdgcn_mfma_f32_16x16x32_bf16(bv[s][db], ap, oaccT[m][db], 0, 0, 0);
      }
    }
    __builtin_amdgcn_s_setprio(0);

    __builtin_amdgcn_s_barrier();
    cur ^= 1;
  }

  // epilogue: reduce lsum partials across the lg-group once, scale, store
  int b = bh >> 3, h = bh & 7;
  #pragma unroll
  for (int m = 0; m < 4; ++m) {
    float v = lsums[m];
    v += __shfl_xor(v, 16);
    v += __shfl_xor(v, 32);
    float inv = 1.0f / v;
    int q = q0 + wave * 64 + m * 16 + lr;
    #pragma unroll
    for (int db = 0; db < 4; ++db) {
      int d0 = db * 16 + lg * 4;
      short4v o;
      #pragma unroll
      for (int r = 0; r < 4; ++r) o[r] = f2bf(oaccT[m][db][r] * inv);
      *(short4v*)&Oh[(size_t)(b * LL + q) * CC + h * 64 + d0] = o;
    }
  }
}

// ---------------- launcher ----------------
extern "C" void kernel_launch(void* const* d_in, const int* in_sizes, int n_in,
                              void* d_out, int out_size, void* d_ws, size_t ws_size,
                              hipStream_t stream) {
  (void)in_sizes; (void)n_in; (void)out_size;
  const float* query = (const float*)d_in[0];
  const float* qpos  = (const float*)d_in[1];
  const float* Wqc = (const float*)d_in[2];
  const float* bqc = (const float*)d_in[3];
  const float* Wqp = (const float*)d_in[4];
  const float* bqp = (const float*)d_in[5];
  const float* Wkc = (const float*)d_in[6];
  const float* bkc = (const float*)d_in[7];
  const float* Wkp = (const float*)d_in[8];
  const float* bkp = (const float*)d_in[9];
  const float* Wv  = (const float*)d_in[10];
  const float* bv  = (const float*)d_in[11];
  const float* Wo  = (const float*)d_in[12];
  const float* bo  = (const float*)d_in[13];

  char* ws = (char*)d_ws;
  if (ws_size < WS_END) return;

  u16*   Xcat     = (u16*)(ws + WS_XCAT);
  u16*   Wcat     = (u16*)(ws + WS_WCAT);
  u16*   Wo_bf    = (u16*)(ws + WS_WO);
  float* bias_cat = (float*)(ws + WS_BIAS);
  u16*   Qh       = (u16*)(ws + WS_QH);
  u16*   Kh       = (u16*)(ws + WS_KH);
  u16*   Vtr      = (u16*)(ws + WS_VT);
  u16*   Oh       = (u16*)(ws + WS_OH);
  float* out      = (float*)d_out;

  pack_all_kernel<<<dim3(9088), dim3(256), 0, stream>>>(
      query, qpos, Wqc, Wqp, Wkc, Wkp, Wv, Wo,
      bqc, bqp, bkc, bkp, bv, Xcat, Wcat, Wo_bf, bias_cat);
  proj_gemm_kernel<<<dim3((MROWS / 128) * (NPROJ / 128)), dim3(256), 0, stream>>>(
      Xcat, Wcat, bias_cat, Qh, Kh, Vtr);
  attn_kernel<<<dim3(512), dim3(256), 0, stream>>>(Qh, Kh, Vtr, Oh);
  out_gemm_kernel<<<dim3((MROWS / 128) * (CC / 128)), dim3(256), 0, stream>>>(
      Oh, Wo_bf, bo, query, out);
}